// Round 4
// baseline (885.927 us; speedup 1.0000x reference)
//
#include <hip/hip_runtime.h>
#include <hip/hip_bf16.h>
#include <cstddef>
#include <cstdint>

#define NN 2048      // nodes (M and K of the big GEMMs)
#define CIN 2
#define HH 32        // hidden
#define EMB 16
#define HOR 12
#define BB 32        // batch
#define TT 16        // time steps
#define GC 128       // 4*HH gate channels
#define XCOLS 1024   // B*T*C
#define HCOLS 1024   // B*H  (GEMM N dim)
#define NT2 64       // full-K: 2048/32 K-tiles (BK=32)

// Tiled fp16 operand layouts (32-k tiles, 8-elem chunks): every MFMA fragment
// is a CONTIGUOUS 16B/lane, 1KB/wave global load -> fragments are loaded
// global -> register -> MFMA directly (no LDS staging in the K-loop).
//   A2t [tt=64][ko=4][row=2048][e=8] : elem ((tt*4+ko)*2048+row)*8+e = A[row][tt*32+ko*8+e]
//   hTt [tt=64][ko=4][col=1024][e=8] : elem ((tt*4+ko)*1024+col)*8+e = h[node=tt*32+ko*8+e][col]
//   B2xt: hi plane same shape as hTt; lo plane at +LOPLANE elements.
#define ATILE_STRIDE 65536   // 4*2048*8 elements per 32-k tile of A
#define BTILE_STRIDE 32768   // 4*1024*8 elements per 32-k tile of B
#define LOPLANE 2097152      // elements per x plane (64*4*1024*8)

typedef __attribute__((ext_vector_type(8))) _Float16 f16x8;
typedef __attribute__((ext_vector_type(16))) float f32x16;

// ---------------------------------------------------------------------------
// Kernel 1: A = softmax(relu(E1 @ E2^T)) -> A2t tiled fp16
// ---------------------------------------------------------------------------
__global__ __launch_bounds__(256) void adj_softmax(const float* __restrict__ E1,
                                                   const float* __restrict__ E2,
                                                   _Float16* __restrict__ A2) {
    const int i = blockIdx.x;
    __shared__ float red[256];
    float e1[EMB];
#pragma unroll
    for (int k = 0; k < EMB; ++k) e1[k] = E1[i * EMB + k];

    float s[8];
    float mx = -1e30f;
#pragma unroll
    for (int q = 0; q < 8; ++q) {
        const int j = q * 256 + threadIdx.x;
        float d = 0.f;
#pragma unroll
        for (int k = 0; k < EMB; ++k) d += e1[k] * E2[j * EMB + k];
        d = fmaxf(d, 0.0f);
        s[q] = d;
        mx = fmaxf(mx, d);
    }
    red[threadIdx.x] = mx;
    __syncthreads();
    for (int off = 128; off > 0; off >>= 1) {
        if (threadIdx.x < off) red[threadIdx.x] = fmaxf(red[threadIdx.x], red[threadIdx.x + off]);
        __syncthreads();
    }
    mx = red[0];
    __syncthreads();

    float sum = 0.f;
#pragma unroll
    for (int q = 0; q < 8; ++q) { s[q] = expf(s[q] - mx); sum += s[q]; }
    red[threadIdx.x] = sum;
    __syncthreads();
    for (int off = 128; off > 0; off >>= 1) {
        if (threadIdx.x < off) red[threadIdx.x] += red[threadIdx.x + off];
        __syncthreads();
    }
    const float inv = 1.0f / red[0];
#pragma unroll
    for (int q = 0; q < 8; ++q) {
        const int j  = q * 256 + threadIdx.x;      // k-index of A row i
        const int tt = j >> 5, ko = (j >> 3) & 3, e = j & 7;
        A2[((size_t)(tt * 4 + ko) * 2048 + i) * 8 + e] = (_Float16)(s[q] * inv);
    }
}

// ---------------------------------------------------------------------------
// Kernel 2: x -> B2xt tiled hi/lo fp16 planes (col = (b*T+t)*C + c).
// ---------------------------------------------------------------------------
__global__ __launch_bounds__(256) void transpose_x(const float* __restrict__ x,
                                                   _Float16* __restrict__ B2x) {
    const int idx = blockIdx.x * 256 + threadIdx.x;
    const int col = idx >> 11;
    const int j   = idx & (NN - 1);               // node index (gemm K dim)
    const int bt  = col >> 1;
    const int c   = col & 1;
    const float v = x[((size_t)bt * NN + j) * CIN + c];
    const _Float16 hi = (_Float16)v;
    const _Float16 lo = (_Float16)(v - (float)hi);
    const int tt = j >> 5, ko = (j >> 3) & 3, e = j & 7;
    const size_t base = ((size_t)(tt * 4 + ko) * 1024 + col) * 8 + e;
    B2x[base] = hi; B2x[base + LOPLANE] = lo;
}

// ---------------------------------------------------------------------------
// Kernel 3: fused full-K fp16 MFMA GEMM (32x32x16) + optional gate epilogue.
// Tile M=32 nodes x N=128 cols, K=2048. Grid 512, 2 blocks/CU, 4 waves.
// NO LDS IN THE K-LOOP: the tiled operand layout makes each MFMA fragment a
// contiguous coalesced 1KB/wave global load, so fragments stream
// global(L2) -> registers -> MFMA. B has zero intra-block reuse (M=32) and
// A's 4x wave-multicast is served by L1, so LDS staging was pure overhead.
// 4-deep named register ring (R/S/T/U): 12 loads outstanding in steady
// state, counted vmcnt via register deps, no barriers across K.
// Two independent acc chains (k-even/k-odd subtiles) break the MFMA
// dependency chain; summed in the epilogue. Bitwise-identical math to the
// LDS version (same bytes, same fragment lanes, same MFMA order).
// XCD swizzle: physical XCD x owns 16 mb x 4 nb -> per-XCD L2 set =
// 2MB A-slab + 2MB hT-col-slab (fits 4MB L2).
// GATE=0: store C directly (AX path; NPROD=2 sums hi+lo planes into acc).
// GATE=1: epilogue computes gates = C*Whr + AX*Wxr + b, LSTM cell update,
//         writes c, tiled hT (ping-pong buffer), h32 on last step.
// ---------------------------------------------------------------------------
template <int NPROD, int GATE>
__global__ __launch_bounds__(256, 2) void gemm_fused(const _Float16* __restrict__ A2,
                                                     const _Float16* __restrict__ B2,
                                                     float* __restrict__ Cout,
                                                     const float* __restrict__ AX,
                                                     const float* __restrict__ Whr,
                                                     const float* __restrict__ Wxr,
                                                     const float* __restrict__ bfold,
                                                     float* __restrict__ cst,
                                                     float* __restrict__ h32,
                                                     _Float16* __restrict__ hTout,
                                                     int t, int last) {
    // LDS only for the gate epilogue: ah[32][129] + weight tables.
    constexpr int AHSZ   = 32 * 129 * 4;           // 16512 B
    constexpr int SMEMSZ = GATE ? (AHSZ + 16384 + 1024 + 512 + 1024) : 16;
    __shared__ __align__(16) char smem[SMEMSZ];

    const int tid  = threadIdx.x;
    const int w    = tid >> 6;
    const int lane = tid & 63;

    // XCD-aware decomposition: physical XCD = wg & 7 (round-robin dispatch).
    // XCD owns 16 consecutive mb x 4 consecutive nb.
    const int wg = blockIdx.x;
    const int x8 = wg & 7;
    const int s  = wg >> 3;                 // 0..63 slot within XCD
    const int mb = (x8 >> 1) * 16 + (s & 15);
    const int nb = (x8 & 1) * 4 + (s >> 4);
    const int m0 = mb * 32;
    const int n0 = nb * 128;

    float* whr_s = nullptr; float* wxr_s = nullptr; float* bfl_s = nullptr; float* axs = nullptr;
    if constexpr (GATE) {
        whr_s = (float*)(smem + AHSZ);
        wxr_s = whr_s + 4096;
        bfl_s = wxr_s + 256;
        axs   = bfl_s + 128;           // [bi 4][which 2][nl 32]
        const int b0c = nb * 4;
#pragma unroll
        for (int r = 0; r < 4; ++r)
            *(float4*)&whr_s[tid * 4 + r * 1024] = *(const float4*)&Whr[tid * 4 + r * 1024];
        if (tid < 64) *(float4*)&wxr_s[tid * 4] = *(const float4*)&Wxr[tid * 4];
        if (tid < 32) *(float4*)&bfl_s[tid * 4] = *(const float4*)&bfold[tid * 4];
        axs[tid] = AX[(size_t)(m0 + (tid & 31)) * XCOLS +
                      ((b0c + (tid >> 6)) * TT + t) * CIN + ((tid >> 5) & 1)];
    }

    // ---- per-lane fragment pointers (tile 0); advance by tile strides.
    // fa0: ko=lg, fa1: ko=2+lg; fb0: ko=lg, fb1: ko=2+lg (col = wc+lrow).
    const int lrow = lane & 31, lg = lane >> 5;
    const int wc = w * 32;
    const _Float16* ga0 = A2 + ((size_t)(lg)     * 2048 + m0 + lrow) * 8;
    const _Float16* ga1 = A2 + ((size_t)(2 + lg) * 2048 + m0 + lrow) * 8;
    const _Float16* gb0 = B2 + ((size_t)(lg)     * 1024 + n0 + wc + lrow) * 8;
    const _Float16* gb1 = B2 + ((size_t)(2 + lg) * 1024 + n0 + wc + lrow) * 8;
    const _Float16 *gc0 = nullptr, *gc1 = nullptr;
    if constexpr (NPROD == 2) { gc0 = gb0 + LOPLANE; gc1 = gb1 + LOPLANE; }

    f32x16 acc0 = (f32x16)(0.0f), acc1 = (f32x16)(0.0f);

    uint4 Ra0, Ra1, Rb0, Rb1, Rc0, Rc1;    // ring set 0
    uint4 Sa0, Sa1, Sb0, Sb1, Sc0, Sc1;    // ring set 1
    uint4 Ta0, Ta1, Tb0, Tb1, Tc0, Tc1;    // ring set 2
    uint4 Ua0, Ua1, Ub0, Ub1, Uc0, Uc1;    // ring set 3

#define LOADSET(P)                                                             \
    P##a0 = *(const uint4*)ga0; ga0 += ATILE_STRIDE;                           \
    P##a1 = *(const uint4*)ga1; ga1 += ATILE_STRIDE;                           \
    P##b0 = *(const uint4*)gb0; gb0 += BTILE_STRIDE;                           \
    P##b1 = *(const uint4*)gb1; gb1 += BTILE_STRIDE;                           \
    if constexpr (NPROD == 2) {                                                \
        P##c0 = *(const uint4*)gc0; gc0 += BTILE_STRIDE;                       \
        P##c1 = *(const uint4*)gc1; gc1 += BTILE_STRIDE;                       \
    }

#define COMPUTE(P) do {                                                        \
    f16x8 fa0 = __builtin_bit_cast(f16x8, P##a0);                              \
    f16x8 fa1 = __builtin_bit_cast(f16x8, P##a1);                              \
    f16x8 fb0 = __builtin_bit_cast(f16x8, P##b0);                              \
    f16x8 fb1 = __builtin_bit_cast(f16x8, P##b1);                              \
    acc0 = __builtin_amdgcn_mfma_f32_32x32x16_f16(fa0, fb0, acc0, 0, 0, 0);    \
    acc1 = __builtin_amdgcn_mfma_f32_32x32x16_f16(fa1, fb1, acc1, 0, 0, 0);    \
    if constexpr (NPROD == 2) {                                                \
        f16x8 fc0 = __builtin_bit_cast(f16x8, P##c0);                          \
        f16x8 fc1 = __builtin_bit_cast(f16x8, P##c1);                          \
        acc0 = __builtin_amdgcn_mfma_f32_32x32x16_f16(fa0, fc0, acc0, 0, 0, 0);\
        acc1 = __builtin_amdgcn_mfma_f32_32x32x16_f16(fa1, fc1, acc1, 0, 0, 0);\
    }                                                                          \
} while (0)

    LOADSET(R)     // tile 0
    LOADSET(S)     // tile 1
    LOADSET(T)     // tile 2
    LOADSET(U)     // tile 3
#pragma unroll 1
    for (int it = 0; it < NT2; it += 4) {
        COMPUTE(R); LOADSET(R)             // tile it+4 (tail over-read in-ws)
        COMPUTE(S); LOADSET(S)             // tile it+5
        COMPUTE(T); LOADSET(T)             // tile it+6
        COMPUTE(U); LOADSET(U)             // tile it+7
    }
#undef LOADSET
#undef COMPUTE

    // ---- C layout per 32x32 acc: col=lane&31, row=(r&3)+8*(r>>2)+4*lg ----
    if constexpr (!GATE) {
        const int colg = n0 + wc + lrow;
#pragma unroll
        for (int r = 0; r < 16; ++r) {
            const int rp = (r & 3) + 8 * (r >> 2) + 4 * lg;
            Cout[(size_t)(m0 + rp) * XCOLS + colg] = acc0[r] + acc1[r];
        }
    } else {
        // stage Ah tile to LDS for the node-major gate pass
        float* ah = (float*)smem;               // [32][129]
#pragma unroll
        for (int r = 0; r < 16; ++r) {
            const int rp = (r & 3) + 8 * (r >> 2) + 4 * lg;
            ah[rp * 129 + wc + lrow] = acc0[r] + acc1[r];
        }
        __syncthreads();

        const int nl2 = tid & 31;               // node within tile
        const int hq  = tid >> 5;               // 0..7 -> h = hq*4+u
        const int b0c = nb * 4;
        const int nd  = m0 + nl2;
        const size_t ntbase = ((size_t)((nd >> 5) * 4 + ((nd >> 3) & 3)) * 1024) * 8 + (nd & 7);

#pragma unroll 1
        for (int bi = 0; bi < 4; ++bi) {
            const float ax0 = axs[bi * 64 + nl2];
            const float ax1 = axs[bi * 64 + 32 + nl2];
            float ar[32];
#pragma unroll
            for (int k = 0; k < 32; ++k) ar[k] = ah[nl2 * 129 + bi * 32 + k];

            float a4[4][4];
#pragma unroll
            for (int u = 0; u < 4; ++u) {
                const int h = hq * 4 + u;
#pragma unroll
                for (int g = 0; g < 4; ++g)
                    a4[u][g] = bfl_s[h * 4 + g] + ax0 * wxr_s[h * 4 + g] + ax1 * wxr_s[128 + h * 4 + g];
            }
#pragma unroll 4
            for (int k = 0; k < 32; ++k) {
                const float av = ar[k];
#pragma unroll
                for (int u = 0; u < 4; ++u) {
                    const float* wp = &whr_s[(k * 32 + hq * 4 + u) * 4];
                    a4[u][0] += av * wp[0];
                    a4[u][1] += av * wp[1];
                    a4[u][2] += av * wp[2];
                    a4[u][3] += av * wp[3];
                }
            }

            const int b = b0c + bi;
            const size_t off = (size_t)nd * HCOLS + b * HH + hq * 4;
            const float4 co = *(const float4*)(cst + off);
            const float cold[4] = {co.x, co.y, co.z, co.w};
            float cn[4], hn[4];
#pragma unroll
            for (int u = 0; u < 4; ++u) {
                const float i_ = 1.0f / (1.0f + expf(-a4[u][0]));
                const float f_ = 1.0f / (1.0f + expf(-a4[u][1]));
                const float o_ = 1.0f / (1.0f + expf(-a4[u][2]));
                const float g_ = tanhf(a4[u][3]);
                const float ct = f_ * cold[u] + i_ * g_;
                cn[u] = ct;
                hn[u] = o_ * tanhf(ct);
            }
            *(float4*)(cst + off) = make_float4(cn[0], cn[1], cn[2], cn[3]);
            if (last) *(float4*)(h32 + off) = make_float4(hn[0], hn[1], hn[2], hn[3]);
#pragma unroll
            for (int u = 0; u < 4; ++u)
                hTout[ntbase + (size_t)(b * HH + hq * 4 + u) * 8] = (_Float16)hn[u];
        }
    }
}

// ---------------------------------------------------------------------------
// Kernel 3c: weight prep. Whr[k][h][g] = Wh[k][g*32+h]; Wxr[c][h][g]; bfold.
// ---------------------------------------------------------------------------
__global__ __launch_bounds__(256) void prep_weights(const float* __restrict__ Wx,
                                                    const float* __restrict__ bx,
                                                    const float* __restrict__ Wh,
                                                    const float* __restrict__ bh,
                                                    float* __restrict__ Whr,
                                                    float* __restrict__ Wxr,
                                                    float* __restrict__ bfold) {
    const int tid = threadIdx.x;
#pragma unroll
    for (int r = 0; r < 16; ++r) {
        const int idx = tid * 16 + r;           // 4096
        const int k = idx >> 7, rem = idx & 127;
        const int h = rem >> 2, g = rem & 3;
        Whr[idx] = Wh[k * GC + g * HH + h];
    }
    {
        const int idx = tid;                    // 256
        const int c = idx >> 7, rem = idx & 127;
        const int h = rem >> 2, g = rem & 3;
        Wxr[idx] = Wx[c * GC + g * HH + h];
    }
    if (tid < 128) {
        const int h = tid >> 2, g = tid & 3;
        bfold[tid] = bx[g * HH + h] + bh[g * HH + h];
    }
}

// ---------------------------------------------------------------------------
// Kernel 4: t=0 gate update only (no recurrent term), 64 nodes x 4 batches.
// ---------------------------------------------------------------------------
__global__ __launch_bounds__(256) void gate_update(const float* __restrict__ AX,
                                                   const float* __restrict__ Whr,
                                                   const float* __restrict__ Wxr,
                                                   const float* __restrict__ bfold,
                                                   float* __restrict__ c,
                                                   float* __restrict__ h32,
                                                   _Float16* __restrict__ hT) {
    const int n0 = blockIdx.x * 64;
    const int b0 = blockIdx.y * 4;
    const int tid = threadIdx.x;
    __shared__ float wxr[256];
    __shared__ float bfl[128];
    __shared__ float axs[2][64];

    if (tid < 64)  *(float4*)&wxr[tid * 4] = *(const float4*)&Wxr[tid * 4];
    if (tid < 32)  *(float4*)&bfl[tid * 4] = *(const float4*)&bfold[tid * 4];

    const int nl = tid & 63;
    const int hq = tid >> 6;

    const int nd = n0 + nl;
    const size_t ntbase = ((size_t)((nd >> 5) * 4 + ((nd >> 3) & 3)) * 1024) * 8 + (nd & 7);

#pragma unroll 1
    for (int bi = 0; bi < 4; ++bi) {
        const int b = b0 + bi;
        if (bi) __syncthreads();
        if (tid < 128) {
            const int which = tid >> 6, nls = tid & 63;
            axs[which][nls] = AX[(size_t)(n0 + nls) * XCOLS + (b * TT + 0) * CIN + which];
        }
        __syncthreads();

        const float ax0 = axs[0][nl], ax1 = axs[1][nl];
        float cn[8], hn[8];
#pragma unroll
        for (int u = 0; u < 8; ++u) {
            const int h = hq * 8 + u;
            float a0 = bfl[h * 4 + 0] + ax0 * wxr[h * 4 + 0] + ax1 * wxr[128 + h * 4 + 0];
            float a1 = bfl[h * 4 + 1] + ax0 * wxr[h * 4 + 1] + ax1 * wxr[128 + h * 4 + 1];
            float a2 = bfl[h * 4 + 2] + ax0 * wxr[h * 4 + 2] + ax1 * wxr[128 + h * 4 + 2];
            float a3 = bfl[h * 4 + 3] + ax0 * wxr[h * 4 + 3] + ax1 * wxr[128 + h * 4 + 3];
            const float i_ = 1.0f / (1.0f + expf(-a0));
            const float f_ = 1.0f / (1.0f + expf(-a1));
            const float o_ = 1.0f / (1.0f + expf(-a2));
            const float g_ = tanhf(a3);
            const float ct = i_ * g_;          // c_old = 0
            (void)f_;
            cn[u] = ct;
            hn[u] = o_ * tanhf(ct);
        }
        const size_t off = (size_t)nd * HCOLS + b * HH + hq * 8;
        *(float4*)(c + off)       = make_float4(cn[0], cn[1], cn[2], cn[3]);
        *(float4*)(c + off + 4)   = make_float4(cn[4], cn[5], cn[6], cn[7]);
        *(float4*)(h32 + off)     = make_float4(hn[0], hn[1], hn[2], hn[3]);
        *(float4*)(h32 + off + 4) = make_float4(hn[4], hn[5], hn[6], hn[7]);
#pragma unroll
        for (int u = 0; u < 8; ++u)
            hT[ntbase + (size_t)(b * HH + hq * 8 + u) * 8] = (_Float16)hn[u];
    }
}

// ---------------------------------------------------------------------------
// Kernel 5: out[b][th][n] = bp[th] + sum_k h[n][b*H+k] * Wp[k][th]
// ---------------------------------------------------------------------------
__global__ __launch_bounds__(256) void head_kernel(const float* __restrict__ h,
                                                   const float* __restrict__ Wp,
                                                   const float* __restrict__ bp,
                                                   float* __restrict__ out) {
    const int idx = blockIdx.x * 256 + threadIdx.x;
    const int b = idx >> 11;
    const int n = idx & (NN - 1);
    float hv[HH];
    const float* hp = h + (size_t)n * HCOLS + b * HH;
#pragma unroll
    for (int k = 0; k < HH; ++k) hv[k] = hp[k];
#pragma unroll
    for (int th = 0; th < HOR; ++th) {
        float acc = bp[th];
#pragma unroll
        for (int k = 0; k < HH; ++k) acc += hv[k] * Wp[k * HOR + th];
        out[((size_t)b * HOR + th) * NN + n] = acc;
    }
}

// ---------------------------------------------------------------------------
extern "C" void kernel_launch(void* const* d_in, const int* in_sizes, int n_in,
                              void* d_out, int out_size, void* d_ws, size_t ws_size,
                              hipStream_t stream) {
    const float* x  = (const float*)d_in[0];
    const float* E1 = (const float*)d_in[1];
    const float* E2 = (const float*)d_in[2];
    const float* Wx = (const float*)d_in[3];
    const float* bx = (const float*)d_in[4];
    const float* Wh = (const float*)d_in[5];
    const float* bh = (const float*)d_in[6];
    const float* Wp = (const float*)d_in[7];
    const float* bp = (const float*)d_in[8];

    char* ws = (char*)d_ws;
    _Float16* A2  = (_Float16*)(ws);                    //  8 MB  tiled A
    _Float16* B2x = (_Float16*)(ws + ( 8ull << 20));    //  8 MB  tiled x hi/lo
    _Float16* hT0 = (_Float16*)(ws + (16ull << 20));    //  4 MB  tiled h (ping)
    _Float16* hT1 = (_Float16*)(ws + (20ull << 20));    //  4 MB  tiled h (pong)
    float* AX   = (float*)(ws + (24ull << 20));         //  8 MB
    float* cst  = (float*)(ws + (32ull << 20));         //  8 MB
    float* h32  = (float*)(ws + (40ull << 20));         //  8 MB
    float* Whr  = (float*)(ws + (48ull << 20));         // 16 KB
    float* Wxr  = (float*)(ws + (48ull << 20) + 65536);
    float* bfold= (float*)(ws + (48ull << 20) + 131072);
    _Float16* hTb[2] = {hT0, hT1};

    adj_softmax<<<NN, 256, 0, stream>>>(E1, E2, A2);
    transpose_x<<<(XCOLS * NN) / 256, 256, 0, stream>>>(x, B2x);
    prep_weights<<<1, 256, 0, stream>>>(Wx, bx, Wh, bh, Whr, Wxr, bfold);

    // x path: AX = A*Xhi + A*Xlo, written directly (no partials)
    gemm_fused<2, 0><<<512, 256, 0, stream>>>(A2, B2x, AX, nullptr, nullptr, nullptr,
                                              nullptr, nullptr, nullptr, nullptr, 0, 0);

    // t = 0: gates from AX only
    gate_update<<<dim3(NN / 64, BB / 4), 256, 0, stream>>>(AX, Whr, Wxr, bfold,
                                                           cst, h32, hTb[0]);
    // t = 1..15: fused GEMM + gate epilogue; hT ping-pong (read prev, write cur)
    for (int t = 1; t < TT; ++t) {
        gemm_fused<1, 1><<<512, 256, 0, stream>>>(A2, hTb[(t + 1) & 1], nullptr, AX,
                                                  Whr, Wxr, bfold, cst, h32,
                                                  hTb[t & 1], t, t == TT - 1 ? 1 : 0);
    }

    head_kernel<<<(BB * NN) / 256, 256, 0, stream>>>(h32, Wp, bp, (float*)d_out);
}

// Round 5
// 747.620 us; speedup vs baseline: 1.1850x; 1.1850x over previous
//
#include <hip/hip_runtime.h>
#include <hip/hip_bf16.h>
#include <cstddef>
#include <cstdint>

#define NN 2048      // nodes (M and K of the big GEMMs)
#define CIN 2
#define HH 32        // hidden
#define EMB 16
#define HOR 12
#define BB 32        // batch
#define TT 16        // time steps
#define GC 128       // 4*HH gate channels
#define XCOLS 1024   // B*T*C
#define HCOLS 1024   // B*H  (GEMM N dim)

// Tiled fp16 operand layouts (32-k tiles, 8-elem chunks), matching the GEMM's
// LDS layout exactly so staging is a LINEAR contiguous copy (and therefore
// directly expressible as global_load_lds: uniform LDS base + lane*16):
//   A2t [tt=64][ko=4][row=2048][e=8] : elem ((tt*4+ko)*2048+row)*8+e = A[row][tt*32+ko*8+e]
//   hTt [tt=64][ko=4][col=1024][e=8] : elem ((tt*4+ko)*1024+col)*8+e = h[node=tt*32+ko*8+e][col]
//   B2xt: hi plane same shape as hTt; lo plane at +LOPLANE elements.
#define ATILE_STRIDE 65536   // 4*2048*8 elements per 32-k tile of A
#define BTILE_STRIDE 32768   // 4*1024*8 elements per 32-k tile of B
#define LOPLANE 2097152      // elements per x plane (64*4*1024*8)

typedef __attribute__((ext_vector_type(8))) _Float16 f16x8;
typedef __attribute__((ext_vector_type(16))) float f32x16;

__device__ __forceinline__ void load_lds16(const void* g, void* l) {
    __builtin_amdgcn_global_load_lds(
        (const __attribute__((address_space(1))) void*)g,
        (__attribute__((address_space(3))) void*)l, 16, 0, 0);
}

// ---------------------------------------------------------------------------
// Kernel 1: A = softmax(relu(E1 @ E2^T)) -> A2t tiled fp16
// ---------------------------------------------------------------------------
__global__ __launch_bounds__(256) void adj_softmax(const float* __restrict__ E1,
                                                   const float* __restrict__ E2,
                                                   _Float16* __restrict__ A2) {
    const int i = blockIdx.x;
    __shared__ float red[256];
    float e1[EMB];
#pragma unroll
    for (int k = 0; k < EMB; ++k) e1[k] = E1[i * EMB + k];

    float s[8];
    float mx = -1e30f;
#pragma unroll
    for (int q = 0; q < 8; ++q) {
        const int j = q * 256 + threadIdx.x;
        float d = 0.f;
#pragma unroll
        for (int k = 0; k < EMB; ++k) d += e1[k] * E2[j * EMB + k];
        d = fmaxf(d, 0.0f);
        s[q] = d;
        mx = fmaxf(mx, d);
    }
    red[threadIdx.x] = mx;
    __syncthreads();
    for (int off = 128; off > 0; off >>= 1) {
        if (threadIdx.x < off) red[threadIdx.x] = fmaxf(red[threadIdx.x], red[threadIdx.x + off]);
        __syncthreads();
    }
    mx = red[0];
    __syncthreads();

    float sum = 0.f;
#pragma unroll
    for (int q = 0; q < 8; ++q) { s[q] = expf(s[q] - mx); sum += s[q]; }
    red[threadIdx.x] = sum;
    __syncthreads();
    for (int off = 128; off > 0; off >>= 1) {
        if (threadIdx.x < off) red[threadIdx.x] += red[threadIdx.x + off];
        __syncthreads();
    }
    const float inv = 1.0f / red[0];
#pragma unroll
    for (int q = 0; q < 8; ++q) {
        const int j  = q * 256 + threadIdx.x;      // k-index of A row i
        const int tt = j >> 5, ko = (j >> 3) & 3, e = j & 7;
        A2[((size_t)(tt * 4 + ko) * 2048 + i) * 8 + e] = (_Float16)(s[q] * inv);
    }
}

// ---------------------------------------------------------------------------
// Kernel 2: x -> B2xt tiled hi/lo fp16 planes (col = (b*T+t)*C + c).
// ---------------------------------------------------------------------------
__global__ __launch_bounds__(256) void transpose_x(const float* __restrict__ x,
                                                   _Float16* __restrict__ B2x) {
    const int idx = blockIdx.x * 256 + threadIdx.x;
    const int col = idx >> 11;
    const int j   = idx & (NN - 1);               // node index (gemm K dim)
    const int bt  = col >> 1;
    const int c   = col & 1;
    const float v = x[((size_t)bt * NN + j) * CIN + c];
    const _Float16 hi = (_Float16)v;
    const _Float16 lo = (_Float16)(v - (float)hi);
    const int tt = j >> 5, ko = (j >> 3) & 3, e = j & 7;
    const size_t base = ((size_t)(tt * 4 + ko) * 1024 + col) * 8 + e;
    B2x[base] = hi; B2x[base + LOPLANE] = lo;
}

// ---------------------------------------------------------------------------
// Kernel 3: fused full-K fp16 MFMA GEMM (32x32x16) + optional gate epilogue.
// Tile M=32 nodes x N=128 cols, K=2048. Grid 512, 2 blocks/CU, 4 waves.
// Staging via global_load_lds (direct HBM/L2 -> LDS DMA, no VGPR round-trip):
// the tiled global layout equals the LDS layout, so every 64-chunk group is
// {uniform LDS base + lane*16} with per-lane global addresses — exactly the
// intrinsic's semantics. m97-style loop: STAGE(next) || COMPUTE(cur), then
// one __syncthreads() per K-step (compiler inserts vmcnt(0) drain there).
// NPROD=1 (recurrent): BK=64, 2 x 20KB buffers. NPROD=2 (x path): BK=32,
// 2 x 18KB buffers. Two acc chains break the MFMA dependency chain.
// XCD swizzle: physical XCD x owns 16 mb x 4 nb -> per-XCD L2 set =
// 2MB A-slab + 2MB hT-col-slab (fits 4MB L2).
// GATE=0: store C directly (AX path; NPROD=2 sums hi+lo planes into acc).
// GATE=1: epilogue computes gates = C*Whr + AX*Wxr + b, LSTM cell update,
//         writes c, tiled hT (ping-pong buffer), h32 on last step.
// ---------------------------------------------------------------------------
template <int NPROD, int GATE>
__global__ __launch_bounds__(256, 2) void gemm_fused(const _Float16* __restrict__ A2,
                                                     const _Float16* __restrict__ B2,
                                                     float* __restrict__ Cout,
                                                     const float* __restrict__ AX,
                                                     const float* __restrict__ Whr,
                                                     const float* __restrict__ Wxr,
                                                     const float* __restrict__ bfold,
                                                     float* __restrict__ cst,
                                                     float* __restrict__ h32,
                                                     _Float16* __restrict__ hTout,
                                                     int t, int last) {
    constexpr int SUBS   = (NPROD == 1) ? 2 : 1;     // 32k-subtiles per K-step
    constexpr int NT     = 2048 / (32 * SUBS);       // K-steps
    constexpr int SUBBUF = 2048 + NPROD * 8192;      // bytes per 32k-subtile
    constexpr int BUF    = SUBS * SUBBUF;            // bytes per LDS buffer
    constexpr int PCH    = 128 + NPROD * 512;        // chunks per subtile
    constexpr int NG     = (SUBS * PCH) / 64;        // 64-chunk groups per step
    constexpr int GMAX   = (NG + 3) / 4;             // groups per wave (<=5)
    constexpr int STAGE_SZ = 2 * BUF;
    constexpr int SMEMSZ = GATE ? (STAGE_SZ + 16384 + 1024 + 512 + 1024) : STAGE_SZ;
    __shared__ __align__(16) char smem[SMEMSZ];

    const int tid  = threadIdx.x;
    const int w    = tid >> 6;
    const int lane = tid & 63;

    // XCD-aware decomposition: physical XCD = wg & 7 (round-robin dispatch).
    // XCD owns 16 consecutive mb x 4 consecutive nb.
    const int wg = blockIdx.x;
    const int x8 = wg & 7;
    const int s  = wg >> 3;                 // 0..63 slot within XCD
    const int mb = (x8 >> 1) * 16 + (s & 15);
    const int nb = (x8 & 1) * 4 + (s >> 4);
    const int m0 = mb * 32;
    const int n0 = nb * 128;

    float* whr_s = nullptr; float* wxr_s = nullptr; float* bfl_s = nullptr; float* axs = nullptr;
    if constexpr (GATE) {
        whr_s = (float*)(smem + STAGE_SZ);
        wxr_s = whr_s + 4096;
        bfl_s = wxr_s + 256;
        axs   = bfl_s + 128;           // [bi 4][which 2][nl 32]
        const int b0c = nb * 4;
#pragma unroll
        for (int r = 0; r < 4; ++r)
            *(float4*)&whr_s[tid * 4 + r * 1024] = *(const float4*)&Whr[tid * 4 + r * 1024];
        if (tid < 64) *(float4*)&wxr_s[tid * 4] = *(const float4*)&Wxr[tid * 4];
        if (tid < 32) *(float4*)&bfl_s[tid * 4] = *(const float4*)&bfold[tid * 4];
        axs[tid] = AX[(size_t)(m0 + (tid & 31)) * XCOLS +
                      ((b0c + (tid >> 6)) * TT + t) * CIN + ((tid >> 5) & 1)];
    }

    // ---- per-wave staging groups. Group g covers chunks [g*64, g*64+64):
    // chunk cid -> subtile s = cid/PCH, r = cid%PCH.
    //   r <  128: A chunk (ko=r>>5, row=r&31),   LDS off = s*SUBBUF + r*16
    //   r >= 128: B chunk r2=r-128 (plane=r2>>9, ko=(r2&511)>>7, col=r2&127),
    //             LDS off = s*SUBBUF + 2048 + r2*16
    // All region boundaries are multiples of 64 -> groups never straddle.
    const _Float16* gp[GMAX];
    int lbase[GMAX];
    int adv[GMAX];
    bool val[GMAX];
#pragma unroll
    for (int i = 0; i < GMAX; ++i) {
        const int g = w + 4 * i;
        val[i] = (g < NG);
        const int gg = val[i] ? g : 0;
        const int cid  = gg * 64 + lane;
        const int cid0 = gg * 64;
        const int su  = cid / PCH,  r  = cid  - su * PCH;
        const int su0 = cid0 / PCH, r0 = cid0 - su0 * PCH;
        if (r < 128) {
            gp[i]  = A2 + ((size_t)((su * 4 + (r >> 5)) * 2048) + m0 + (r & 31)) * 8;
            adv[i] = SUBS * ATILE_STRIDE;
        } else {
            const int r2 = r - 128;
            gp[i]  = B2 + (size_t)(r2 >> 9) * LOPLANE
                        + ((size_t)((su * 4 + ((r2 & 511) >> 7)) * 1024) + n0 + (r2 & 127)) * 8;
            adv[i] = SUBS * BTILE_STRIDE;
        }
        lbase[i] = su0 * SUBBUF + (r0 < 128 ? r0 * 16 : 2048 + (r0 - 128) * 16);
    }

    // ---- fragment offsets: lane lrow = lane&31, lg = lane>>5; wave cols w*32
    const int lrow = lane & 31, lg = lane >> 5;
    const int wc = w * 32;
    const int aoff0 = lg * 512 + lrow * 16;               // ks=0 (ko = lg)
    const int aoff1 = 1024 + lg * 512 + lrow * 16;        // ks=1 (ko = 2+lg)
    const int boff0 = 2048 + lg * 2048 + (wc + lrow) * 16;
    const int boff1 = 2048 + 4096 + lg * 2048 + (wc + lrow) * 16;

    f32x16 acc0 = (f32x16)(0.0f), acc1 = (f32x16)(0.0f);

#define STAGE(BUFI) do {                                                       \
    char* lb = smem + (BUFI) * BUF;                                            \
    _Pragma("unroll")                                                          \
    for (int i = 0; i < GMAX; ++i) if (val[i]) {                               \
        load_lds16(gp[i], lb + lbase[i]);                                      \
        gp[i] += adv[i];                                                       \
    }                                                                          \
} while (0)

#define COMPUTE(BUFI) do {                                                     \
    const char* sb = smem + (BUFI) * BUF;                                      \
    _Pragma("unroll")                                                          \
    for (int su = 0; su < SUBS; ++su) {                                        \
        const char* st = sb + su * SUBBUF;                                     \
        f16x8 fa0 = *(const f16x8*)(st + aoff0);                               \
        f16x8 fa1 = *(const f16x8*)(st + aoff1);                               \
        f16x8 fb0 = *(const f16x8*)(st + boff0);                               \
        f16x8 fb1 = *(const f16x8*)(st + boff1);                               \
        acc0 = __builtin_amdgcn_mfma_f32_32x32x16_f16(fa0, fb0, acc0, 0, 0, 0);\
        acc1 = __builtin_amdgcn_mfma_f32_32x32x16_f16(fa1, fb1, acc1, 0, 0, 0);\
        if constexpr (NPROD == 2) {                                            \
            f16x8 fc0 = *(const f16x8*)(st + boff0 + 8192);                    \
            f16x8 fc1 = *(const f16x8*)(st + boff1 + 8192);                    \
            acc0 = __builtin_amdgcn_mfma_f32_32x32x16_f16(fa0, fc0, acc0, 0, 0, 0); \
            acc1 = __builtin_amdgcn_mfma_f32_32x32x16_f16(fa1, fc1, acc1, 0, 0, 0); \
        }                                                                      \
    }                                                                          \
} while (0)

    STAGE(0);                      // tile 0
    __syncthreads();               // vmcnt(0) drain: buf0 ready
#pragma unroll 1
    for (int it = 0; it < NT; ++it) {
        if (it + 1 < NT) STAGE((it + 1) & 1);   // prefetch next tile
        COMPUTE(it & 1);                        // overlaps with the DMA
        __syncthreads();                        // drain -> next buf ready;
    }                                           // also guards buf overwrite
#undef STAGE
#undef COMPUTE

    // ---- C layout per 32x32 acc: col=lane&31, row=(r&3)+8*(r>>2)+4*lg ----
    if constexpr (!GATE) {
        const int colg = n0 + wc + lrow;
#pragma unroll
        for (int r = 0; r < 16; ++r) {
            const int rp = (r & 3) + 8 * (r >> 2) + 4 * lg;
            Cout[(size_t)(m0 + rp) * XCOLS + colg] = acc0[r] + acc1[r];
        }
    } else {
        // stage Ah tile to LDS for the node-major gate pass (overlays staging)
        float* ah = (float*)smem;               // [32][129]
#pragma unroll
        for (int r = 0; r < 16; ++r) {
            const int rp = (r & 3) + 8 * (r >> 2) + 4 * lg;
            ah[rp * 129 + wc + lrow] = acc0[r] + acc1[r];
        }
        __syncthreads();

        const int nl2 = tid & 31;               // node within tile
        const int hq  = tid >> 5;               // 0..7 -> h = hq*4+u
        const int b0c = nb * 4;
        const int nd  = m0 + nl2;
        const size_t ntbase = ((size_t)((nd >> 5) * 4 + ((nd >> 3) & 3)) * 1024) * 8 + (nd & 7);

#pragma unroll 1
        for (int bi = 0; bi < 4; ++bi) {
            const float ax0 = axs[bi * 64 + nl2];
            const float ax1 = axs[bi * 64 + 32 + nl2];
            float ar[32];
#pragma unroll
            for (int k = 0; k < 32; ++k) ar[k] = ah[nl2 * 129 + bi * 32 + k];

            float a4[4][4];
#pragma unroll
            for (int u = 0; u < 4; ++u) {
                const int h = hq * 4 + u;
#pragma unroll
                for (int g = 0; g < 4; ++g)
                    a4[u][g] = bfl_s[h * 4 + g] + ax0 * wxr_s[h * 4 + g] + ax1 * wxr_s[128 + h * 4 + g];
            }
#pragma unroll 4
            for (int k = 0; k < 32; ++k) {
                const float av = ar[k];
#pragma unroll
                for (int u = 0; u < 4; ++u) {
                    const float* wp = &whr_s[(k * 32 + hq * 4 + u) * 4];
                    a4[u][0] += av * wp[0];
                    a4[u][1] += av * wp[1];
                    a4[u][2] += av * wp[2];
                    a4[u][3] += av * wp[3];
                }
            }

            const int b = b0c + bi;
            const size_t off = (size_t)nd * HCOLS + b * HH + hq * 4;
            const float4 co = *(const float4*)(cst + off);
            const float cold[4] = {co.x, co.y, co.z, co.w};
            float cn[4], hn[4];
#pragma unroll
            for (int u = 0; u < 4; ++u) {
                const float i_ = 1.0f / (1.0f + expf(-a4[u][0]));
                const float f_ = 1.0f / (1.0f + expf(-a4[u][1]));
                const float o_ = 1.0f / (1.0f + expf(-a4[u][2]));
                const float g_ = tanhf(a4[u][3]);
                const float ct = f_ * cold[u] + i_ * g_;
                cn[u] = ct;
                hn[u] = o_ * tanhf(ct);
            }
            *(float4*)(cst + off) = make_float4(cn[0], cn[1], cn[2], cn[3]);
            if (last) *(float4*)(h32 + off) = make_float4(hn[0], hn[1], hn[2], hn[3]);
#pragma unroll
            for (int u = 0; u < 4; ++u)
                hTout[ntbase + (size_t)(b * HH + hq * 4 + u) * 8] = (_Float16)hn[u];
        }
    }
}

// ---------------------------------------------------------------------------
// Kernel 3c: weight prep. Whr[k][h][g] = Wh[k][g*32+h]; Wxr[c][h][g]; bfold.
// ---------------------------------------------------------------------------
__global__ __launch_bounds__(256) void prep_weights(const float* __restrict__ Wx,
                                                    const float* __restrict__ bx,
                                                    const float* __restrict__ Wh,
                                                    const float* __restrict__ bh,
                                                    float* __restrict__ Whr,
                                                    float* __restrict__ Wxr,
                                                    float* __restrict__ bfold) {
    const int tid = threadIdx.x;
#pragma unroll
    for (int r = 0; r < 16; ++r) {
        const int idx = tid * 16 + r;           // 4096
        const int k = idx >> 7, rem = idx & 127;
        const int h = rem >> 2, g = rem & 3;
        Whr[idx] = Wh[k * GC + g * HH + h];
    }
    {
        const int idx = tid;                    // 256
        const int c = idx >> 7, rem = idx & 127;
        const int h = rem >> 2, g = rem & 3;
        Wxr[idx] = Wx[c * GC + g * HH + h];
    }
    if (tid < 128) {
        const int h = tid >> 2, g = tid & 3;
        bfold[tid] = bx[g * HH + h] + bh[g * HH + h];
    }
}

// ---------------------------------------------------------------------------
// Kernel 4: t=0 gate update only (no recurrent term), 64 nodes x 4 batches.
// ---------------------------------------------------------------------------
__global__ __launch_bounds__(256) void gate_update(const float* __restrict__ AX,
                                                   const float* __restrict__ Whr,
                                                   const float* __restrict__ Wxr,
                                                   const float* __restrict__ bfold,
                                                   float* __restrict__ c,
                                                   float* __restrict__ h32,
                                                   _Float16* __restrict__ hT) {
    const int n0 = blockIdx.x * 64;
    const int b0 = blockIdx.y * 4;
    const int tid = threadIdx.x;
    __shared__ float wxr[256];
    __shared__ float bfl[128];
    __shared__ float axs[2][64];

    if (tid < 64)  *(float4*)&wxr[tid * 4] = *(const float4*)&Wxr[tid * 4];
    if (tid < 32)  *(float4*)&bfl[tid * 4] = *(const float4*)&bfold[tid * 4];

    const int nl = tid & 63;
    const int hq = tid >> 6;

    const int nd = n0 + nl;
    const size_t ntbase = ((size_t)((nd >> 5) * 4 + ((nd >> 3) & 3)) * 1024) * 8 + (nd & 7);

#pragma unroll 1
    for (int bi = 0; bi < 4; ++bi) {
        const int b = b0 + bi;
        if (bi) __syncthreads();
        if (tid < 128) {
            const int which = tid >> 6, nls = tid & 63;
            axs[which][nls] = AX[(size_t)(n0 + nls) * XCOLS + (b * TT + 0) * CIN + which];
        }
        __syncthreads();

        const float ax0 = axs[0][nl], ax1 = axs[1][nl];
        float cn[8], hn[8];
#pragma unroll
        for (int u = 0; u < 8; ++u) {
            const int h = hq * 8 + u;
            float a0 = bfl[h * 4 + 0] + ax0 * wxr[h * 4 + 0] + ax1 * wxr[128 + h * 4 + 0];
            float a1 = bfl[h * 4 + 1] + ax0 * wxr[h * 4 + 1] + ax1 * wxr[128 + h * 4 + 1];
            float a2 = bfl[h * 4 + 2] + ax0 * wxr[h * 4 + 2] + ax1 * wxr[128 + h * 4 + 2];
            float a3 = bfl[h * 4 + 3] + ax0 * wxr[h * 4 + 3] + ax1 * wxr[128 + h * 4 + 3];
            const float i_ = 1.0f / (1.0f + expf(-a0));
            const float f_ = 1.0f / (1.0f + expf(-a1));
            const float o_ = 1.0f / (1.0f + expf(-a2));
            const float g_ = tanhf(a3);
            const float ct = i_ * g_;          // c_old = 0
            (void)f_;
            cn[u] = ct;
            hn[u] = o_ * tanhf(ct);
        }
        const size_t off = (size_t)nd * HCOLS + b * HH + hq * 8;
        *(float4*)(c + off)       = make_float4(cn[0], cn[1], cn[2], cn[3]);
        *(float4*)(c + off + 4)   = make_float4(cn[4], cn[5], cn[6], cn[7]);
        *(float4*)(h32 + off)     = make_float4(hn[0], hn[1], hn[2], hn[3]);
        *(float4*)(h32 + off + 4) = make_float4(hn[4], hn[5], hn[6], hn[7]);
#pragma unroll
        for (int u = 0; u < 8; ++u)
            hT[ntbase + (size_t)(b * HH + hq * 8 + u) * 8] = (_Float16)hn[u];
    }
}

// ---------------------------------------------------------------------------
// Kernel 5: out[b][th][n] = bp[th] + sum_k h[n][b*H+k] * Wp[k][th]
// ---------------------------------------------------------------------------
__global__ __launch_bounds__(256) void head_kernel(const float* __restrict__ h,
                                                   const float* __restrict__ Wp,
                                                   const float* __restrict__ bp,
                                                   float* __restrict__ out) {
    const int idx = blockIdx.x * 256 + threadIdx.x;
    const int b = idx >> 11;
    const int n = idx & (NN - 1);
    float hv[HH];
    const float* hp = h + (size_t)n * HCOLS + b * HH;
#pragma unroll
    for (int k = 0; k < HH; ++k) hv[k] = hp[k];
#pragma unroll
    for (int th = 0; th < HOR; ++th) {
        float acc = bp[th];
#pragma unroll
        for (int k = 0; k < HH; ++k) acc += hv[k] * Wp[k * HOR + th];
        out[((size_t)b * HOR + th) * NN + n] = acc;
    }
}

// ---------------------------------------------------------------------------
extern "C" void kernel_launch(void* const* d_in, const int* in_sizes, int n_in,
                              void* d_out, int out_size, void* d_ws, size_t ws_size,
                              hipStream_t stream) {
    const float* x  = (const float*)d_in[0];
    const float* E1 = (const float*)d_in[1];
    const float* E2 = (const float*)d_in[2];
    const float* Wx = (const float*)d_in[3];
    const float* bx = (const float*)d_in[4];
    const float* Wh = (const float*)d_in[5];
    const float* bh = (const float*)d_in[6];
    const float* Wp = (const float*)d_in[7];
    const float* bp = (const float*)d_in[8];

    char* ws = (char*)d_ws;
    _Float16* A2  = (_Float16*)(ws);                    //  8 MB  tiled A
    _Float16* B2x = (_Float16*)(ws + ( 8ull << 20));    //  8 MB  tiled x hi/lo
    _Float16* hT0 = (_Float16*)(ws + (16ull << 20));    //  4 MB  tiled h (ping)
    _Float16* hT1 = (_Float16*)(ws + (20ull << 20));    //  4 MB  tiled h (pong)
    float* AX   = (float*)(ws + (24ull << 20));         //  8 MB
    float* cst  = (float*)(ws + (32ull << 20));         //  8 MB
    float* h32  = (float*)(ws + (40ull << 20));         //  8 MB
    float* Whr  = (float*)(ws + (48ull << 20));         // 16 KB
    float* Wxr  = (float*)(ws + (48ull << 20) + 65536);
    float* bfold= (float*)(ws + (48ull << 20) + 131072);
    _Float16* hTb[2] = {hT0, hT1};

    adj_softmax<<<NN, 256, 0, stream>>>(E1, E2, A2);
    transpose_x<<<(XCOLS * NN) / 256, 256, 0, stream>>>(x, B2x);
    prep_weights<<<1, 256, 0, stream>>>(Wx, bx, Wh, bh, Whr, Wxr, bfold);

    // x path: AX = A*Xhi + A*Xlo, written directly (no partials)
    gemm_fused<2, 0><<<512, 256, 0, stream>>>(A2, B2x, AX, nullptr, nullptr, nullptr,
                                              nullptr, nullptr, nullptr, nullptr, 0, 0);

    // t = 0: gates from AX only
    gate_update<<<dim3(NN / 64, BB / 4), 256, 0, stream>>>(AX, Whr, Wxr, bfold,
                                                           cst, h32, hTb[0]);
    // t = 1..15: fused GEMM + gate epilogue; hT ping-pong (read prev, write cur)
    for (int t = 1; t < TT; ++t) {
        gemm_fused<1, 1><<<512, 256, 0, stream>>>(A2, hTb[(t + 1) & 1], nullptr, AX,
                                                  Whr, Wxr, bfold, cst, h32,
                                                  hTb[t & 1], t, t == TT - 1 ? 1 : 0);
    }

    head_kernel<<<(BB * NN) / 256, 256, 0, stream>>>(h32, Wp, bp, (float*)d_out);
}

// Round 6
// 695.977 us; speedup vs baseline: 1.2729x; 1.0742x over previous
//
#include <hip/hip_runtime.h>
#include <hip/hip_bf16.h>
#include <cstddef>
#include <cstdint>

#define NN 2048      // nodes (M and K of the big GEMMs)
#define CIN 2
#define HH 32        // hidden
#define EMB 16
#define HOR 12
#define BB 32        // batch
#define TT 16        // time steps
#define GC 128       // 4*HH gate channels
#define XCOLS 1024   // B*T*C
#define HCOLS 1024   // B*H  (GEMM N dim)

// Tiled fp16 operand layouts (32-k tiles, 8-elem chunks), matching the GEMM's
// LDS layout exactly so staging is a LINEAR contiguous copy (and therefore
// directly expressible as global_load_lds: uniform LDS base + lane*16):
//   A2t [tt=64][ko=4][row=2048][e=8] : elem ((tt*4+ko)*2048+row)*8+e = A[row][tt*32+ko*8+e]
//   hTt [tt=64][ko=4][col=1024][e=8] : elem ((tt*4+ko)*1024+col)*8+e = h[node=tt*32+ko*8+e][col]
//   B2xt: hi plane same shape as hTt; lo plane at +LOPLANE elements.
#define ATILE_STRIDE 65536   // 4*2048*8 elements per 32-k tile of A
#define BTILE_STRIDE 32768   // 4*1024*8 elements per 32-k tile of B
#define LOPLANE 2097152      // elements per x plane (64*4*1024*8)

typedef __attribute__((ext_vector_type(8))) _Float16 f16x8;
typedef __attribute__((ext_vector_type(16))) float f32x16;

__device__ __forceinline__ void load_lds16(const void* g, void* l) {
    __builtin_amdgcn_global_load_lds(
        (const __attribute__((address_space(1))) void*)g,
        (__attribute__((address_space(3))) void*)l, 16, 0, 0);
}

// ---------------------------------------------------------------------------
// Kernel 1: A = softmax(relu(E1 @ E2^T)) -> A2t tiled fp16
// ---------------------------------------------------------------------------
__global__ __launch_bounds__(256) void adj_softmax(const float* __restrict__ E1,
                                                   const float* __restrict__ E2,
                                                   _Float16* __restrict__ A2) {
    const int i = blockIdx.x;
    __shared__ float red[256];
    float e1[EMB];
#pragma unroll
    for (int k = 0; k < EMB; ++k) e1[k] = E1[i * EMB + k];

    float s[8];
    float mx = -1e30f;
#pragma unroll
    for (int q = 0; q < 8; ++q) {
        const int j = q * 256 + threadIdx.x;
        float d = 0.f;
#pragma unroll
        for (int k = 0; k < EMB; ++k) d += e1[k] * E2[j * EMB + k];
        d = fmaxf(d, 0.0f);
        s[q] = d;
        mx = fmaxf(mx, d);
    }
    red[threadIdx.x] = mx;
    __syncthreads();
    for (int off = 128; off > 0; off >>= 1) {
        if (threadIdx.x < off) red[threadIdx.x] = fmaxf(red[threadIdx.x], red[threadIdx.x + off]);
        __syncthreads();
    }
    mx = red[0];
    __syncthreads();

    float sum = 0.f;
#pragma unroll
    for (int q = 0; q < 8; ++q) { s[q] = expf(s[q] - mx); sum += s[q]; }
    red[threadIdx.x] = sum;
    __syncthreads();
    for (int off = 128; off > 0; off >>= 1) {
        if (threadIdx.x < off) red[threadIdx.x] += red[threadIdx.x + off];
        __syncthreads();
    }
    const float inv = 1.0f / red[0];
#pragma unroll
    for (int q = 0; q < 8; ++q) {
        const int j  = q * 256 + threadIdx.x;      // k-index of A row i
        const int tt = j >> 5, ko = (j >> 3) & 3, e = j & 7;
        A2[((size_t)(tt * 4 + ko) * 2048 + i) * 8 + e] = (_Float16)(s[q] * inv);
    }
}

// ---------------------------------------------------------------------------
// Kernel 2: x -> B2xt tiled hi/lo fp16 planes (col = (b*T+t)*C + c).
// ---------------------------------------------------------------------------
__global__ __launch_bounds__(256) void transpose_x(const float* __restrict__ x,
                                                   _Float16* __restrict__ B2x) {
    const int idx = blockIdx.x * 256 + threadIdx.x;
    const int col = idx >> 11;
    const int j   = idx & (NN - 1);               // node index (gemm K dim)
    const int bt  = col >> 1;
    const int c   = col & 1;
    const float v = x[((size_t)bt * NN + j) * CIN + c];
    const _Float16 hi = (_Float16)v;
    const _Float16 lo = (_Float16)(v - (float)hi);
    const int tt = j >> 5, ko = (j >> 3) & 3, e = j & 7;
    const size_t base = ((size_t)(tt * 4 + ko) * 1024 + col) * 8 + e;
    B2x[base] = hi; B2x[base + LOPLANE] = lo;
}

// ---------------------------------------------------------------------------
// Kernel 3: fused full-K fp16 MFMA GEMM (32x32x16) + optional gate epilogue.
// Tile M=32 nodes x N=128 cols, K=2048, BK=32 (NT=64 steps). Grid 512,
// 2 blocks/CU, 4 waves. Staging via global_load_lds DMA.
// PIPELINE (T3/T4): 4 LDS buffers, prefetch depth 2, COUNTED vmcnt across
// raw s_barriers — never drains to 0 in the main loop. Per step:
//   STAGE(tile it+2) ; s_waitcnt vmcnt(2c) ; s_barrier ; COMPUTE(tile it)
// c = per-wave DMA count (waves 0-1: 3, waves 2-3: 2 for NPROD=1; 5/4 for
// NPROD=2). vmcnt retires in order -> vmcnt(2c) == "tile it landed".
// WAR-safe with 4 bufs / depth 2: STAGE targets buf (it+2)&3 == (it-2)&3,
// whose readers (COMPUTE it-2) all finished before barrier(it-1), which
// precedes this STAGE in program order.
// XCD swizzle: physical XCD x owns 16 mb x 4 nb -> per-XCD L2 set =
// 2MB A-slab + 2MB hT-col-slab (fits 4MB L2).
// GATE=0: store C directly (AX path; NPROD=2 sums hi+lo planes into acc).
// GATE=1: epilogue computes gates = C*Whr + AX*Wxr + b, LSTM cell update,
//         writes c, tiled hT (ping-pong buffer), h32 on last step.
// ---------------------------------------------------------------------------
template <int NPROD, int GATE>
__global__ __launch_bounds__(256, 2) void gemm_fused(const _Float16* __restrict__ A2,
                                                     const _Float16* __restrict__ B2,
                                                     float* __restrict__ Cout,
                                                     const float* __restrict__ AX,
                                                     const float* __restrict__ Whr,
                                                     const float* __restrict__ Wxr,
                                                     const float* __restrict__ bfold,
                                                     float* __restrict__ cst,
                                                     float* __restrict__ h32,
                                                     _Float16* __restrict__ hTout,
                                                     int t, int last) {
    constexpr int NT     = 64;                       // K-steps (BK=32)
    constexpr int BUF    = 2048 + NPROD * 8192;      // bytes per buffer
    constexpr int PCH    = 128 + NPROD * 512;        // 16B chunks per step
    constexpr int NG     = PCH / 64;                 // 64-chunk groups (10|18)
    constexpr int GMAX   = (NG + 3) / 4;             // groups per wave
    constexpr int STAGE_SZ = 4 * BUF;
    constexpr int SMEMSZ = GATE ? (STAGE_SZ + 16384 + 1024 + 512 + 1024) : STAGE_SZ;
    __shared__ __align__(16) char smem[SMEMSZ];

    const int tid  = threadIdx.x;
    const int w    = tid >> 6;
    const int lane = tid & 63;

    // XCD-aware decomposition: physical XCD = wg & 7 (round-robin dispatch).
    // XCD owns 16 consecutive mb x 4 consecutive nb.
    const int wg = blockIdx.x;
    const int x8 = wg & 7;
    const int s  = wg >> 3;                 // 0..63 slot within XCD
    const int mb = (x8 >> 1) * 16 + (s & 15);
    const int nb = (x8 & 1) * 4 + (s >> 4);
    const int m0 = mb * 32;
    const int n0 = nb * 128;

    float* whr_s = nullptr; float* wxr_s = nullptr; float* bfl_s = nullptr; float* axs = nullptr;
    if constexpr (GATE) {
        whr_s = (float*)(smem + STAGE_SZ);
        wxr_s = whr_s + 4096;
        bfl_s = wxr_s + 256;
        axs   = bfl_s + 128;           // [bi 4][which 2][nl 32]
        const int b0c = nb * 4;
#pragma unroll
        for (int r = 0; r < 4; ++r)
            *(float4*)&whr_s[tid * 4 + r * 1024] = *(const float4*)&Whr[tid * 4 + r * 1024];
        if (tid < 64) *(float4*)&wxr_s[tid * 4] = *(const float4*)&Wxr[tid * 4];
        if (tid < 32) *(float4*)&bfl_s[tid * 4] = *(const float4*)&bfold[tid * 4];
        axs[tid] = AX[(size_t)(m0 + (tid & 31)) * XCOLS +
                      ((b0c + (tid >> 6)) * TT + t) * CIN + ((tid >> 5) & 1)];
    }

    // ---- per-wave staging groups. Group g covers chunks [g*64, g*64+64):
    //   cid <  128: A chunk (ko=cid>>5, row=cid&31), LDS off = cid*16
    //   cid >= 128: B chunk r2=cid-128 (plane=r2>>9, ko=(r2&511)>>7,
    //               col=r2&127), LDS off = 2048 + r2*16
    const _Float16* gp[GMAX];
    int lbase[GMAX];
    int adv[GMAX];
    bool val[GMAX];
#pragma unroll
    for (int i = 0; i < GMAX; ++i) {
        const int g = w + 4 * i;
        val[i] = (g < NG);
        const int gg = val[i] ? g : 0;
        const int cid  = gg * 64 + lane;
        const int cid0 = gg * 64;
        if (cid < 128) {
            gp[i]  = A2 + ((size_t)((cid >> 5) * 2048) + m0 + (cid & 31)) * 8;
            adv[i] = ATILE_STRIDE;
        } else {
            const int r2 = cid - 128;
            gp[i]  = B2 + (size_t)(r2 >> 9) * LOPLANE
                        + ((size_t)(((r2 & 511) >> 7) * 1024) + n0 + (r2 & 127)) * 8;
            adv[i] = BTILE_STRIDE;
        }
        lbase[i] = (cid0 < 128) ? cid0 * 16 : 2048 + (cid0 - 128) * 16;
    }

    // ---- fragment offsets: lane lrow = lane&31, lg = lane>>5; wave cols w*32
    const int lrow = lane & 31, lg = lane >> 5;
    const int wc = w * 32;
    const int aoff0 = lg * 512 + lrow * 16;               // ks=0 (ko = lg)
    const int aoff1 = 1024 + lg * 512 + lrow * 16;        // ks=1 (ko = 2+lg)
    const int boff0 = 2048 + lg * 2048 + (wc + lrow) * 16;
    const int boff1 = 2048 + 4096 + lg * 2048 + (wc + lrow) * 16;

    f32x16 acc0 = (f32x16)(0.0f), acc1 = (f32x16)(0.0f);

#define STAGE(BUFI) do {                                                       \
    char* lb = smem + (BUFI) * BUF;                                            \
    _Pragma("unroll")                                                          \
    for (int i = 0; i < GMAX; ++i) if (val[i]) {                               \
        load_lds16(gp[i], lb + lbase[i]);                                      \
        gp[i] += adv[i];                                                       \
    }                                                                          \
} while (0)

// counted vmcnt: wave-uniform branch picks the literal for this wave's c.
#define VMW(NHI, NLO) do {                                                     \
    if (w < 2) asm volatile("s_waitcnt vmcnt(" #NHI ")" ::: "memory");         \
    else       asm volatile("s_waitcnt vmcnt(" #NLO ")" ::: "memory");         \
} while (0)

#define BAR() do {                                                             \
    __builtin_amdgcn_s_barrier();                                              \
    asm volatile("" ::: "memory");                                             \
} while (0)

#define COMPUTE(BUFI) do {                                                     \
    const char* st = smem + (BUFI) * BUF;                                      \
    f16x8 fa0 = *(const f16x8*)(st + aoff0);                                   \
    f16x8 fa1 = *(const f16x8*)(st + aoff1);                                   \
    f16x8 fb0 = *(const f16x8*)(st + boff0);                                   \
    f16x8 fb1 = *(const f16x8*)(st + boff1);                                   \
    acc0 = __builtin_amdgcn_mfma_f32_32x32x16_f16(fa0, fb0, acc0, 0, 0, 0);    \
    acc1 = __builtin_amdgcn_mfma_f32_32x32x16_f16(fa1, fb1, acc1, 0, 0, 0);    \
    if constexpr (NPROD == 2) {                                                \
        f16x8 fc0 = *(const f16x8*)(st + boff0 + 8192);                        \
        f16x8 fc1 = *(const f16x8*)(st + boff1 + 8192);                        \
        acc0 = __builtin_amdgcn_mfma_f32_32x32x16_f16(fa0, fc0, acc0, 0, 0, 0);\
        acc1 = __builtin_amdgcn_mfma_f32_32x32x16_f16(fa1, fc1, acc1, 0, 0, 0);\
    }                                                                          \
} while (0)

    STAGE(0);                      // tile 0
    STAGE(1);                      // tile 1
#pragma unroll 1
    for (int it = 0; it < NT - 2; ++it) {
        STAGE((it + 2) & 3);                       // prefetch depth 2
        if constexpr (NPROD == 1) VMW(6, 4); else VMW(10, 8);
        BAR();
        COMPUTE(it & 3);
    }
    if constexpr (NPROD == 1) VMW(3, 2); else VMW(5, 4);
    BAR();
    COMPUTE((NT - 2) & 3);
    asm volatile("s_waitcnt vmcnt(0)" ::: "memory");
    BAR();
    COMPUTE((NT - 1) & 3);
#undef STAGE
#undef VMW
#undef BAR
#undef COMPUTE

    // ---- C layout per 32x32 acc: col=lane&31, row=(r&3)+8*(r>>2)+4*lg ----
    if constexpr (!GATE) {
        const int colg = n0 + wc + lrow;
#pragma unroll
        for (int r = 0; r < 16; ++r) {
            const int rp = (r & 3) + 8 * (r >> 2) + 4 * lg;
            Cout[(size_t)(m0 + rp) * XCOLS + colg] = acc0[r] + acc1[r];
        }
    } else {
        // stage Ah tile to LDS for the node-major gate pass. ah occupies
        // bufs 0-1 (16512 <= 2*BUF); final COMPUTE read buf 3 -> disjoint.
        float* ah = (float*)smem;               // [32][129]
#pragma unroll
        for (int r = 0; r < 16; ++r) {
            const int rp = (r & 3) + 8 * (r >> 2) + 4 * lg;
            ah[rp * 129 + wc + lrow] = acc0[r] + acc1[r];
        }
        __syncthreads();

        const int nl2 = tid & 31;               // node within tile
        const int hq  = tid >> 5;               // 0..7 -> h = hq*4+u
        const int b0c = nb * 4;
        const int nd  = m0 + nl2;
        const size_t ntbase = ((size_t)((nd >> 5) * 4 + ((nd >> 3) & 3)) * 1024) * 8 + (nd & 7);

#pragma unroll 1
        for (int bi = 0; bi < 4; ++bi) {
            const float ax0 = axs[bi * 64 + nl2];
            const float ax1 = axs[bi * 64 + 32 + nl2];
            float ar[32];
#pragma unroll
            for (int k = 0; k < 32; ++k) ar[k] = ah[nl2 * 129 + bi * 32 + k];

            float a4[4][4];
#pragma unroll
            for (int u = 0; u < 4; ++u) {
                const int h = hq * 4 + u;
#pragma unroll
                for (int g = 0; g < 4; ++g)
                    a4[u][g] = bfl_s[h * 4 + g] + ax0 * wxr_s[h * 4 + g] + ax1 * wxr_s[128 + h * 4 + g];
            }
#pragma unroll 4
            for (int k = 0; k < 32; ++k) {
                const float av = ar[k];
#pragma unroll
                for (int u = 0; u < 4; ++u) {
                    const float* wp = &whr_s[(k * 32 + hq * 4 + u) * 4];
                    a4[u][0] += av * wp[0];
                    a4[u][1] += av * wp[1];
                    a4[u][2] += av * wp[2];
                    a4[u][3] += av * wp[3];
                }
            }

            const int b = b0c + bi;
            const size_t off = (size_t)nd * HCOLS + b * HH + hq * 4;
            const float4 co = *(const float4*)(cst + off);
            const float cold[4] = {co.x, co.y, co.z, co.w};
            float cn[4], hn[4];
#pragma unroll
            for (int u = 0; u < 4; ++u) {
                const float i_ = 1.0f / (1.0f + expf(-a4[u][0]));
                const float f_ = 1.0f / (1.0f + expf(-a4[u][1]));
                const float o_ = 1.0f / (1.0f + expf(-a4[u][2]));
                const float g_ = tanhf(a4[u][3]);
                const float ct = f_ * cold[u] + i_ * g_;
                cn[u] = ct;
                hn[u] = o_ * tanhf(ct);
            }
            *(float4*)(cst + off) = make_float4(cn[0], cn[1], cn[2], cn[3]);
            if (last) *(float4*)(h32 + off) = make_float4(hn[0], hn[1], hn[2], hn[3]);
#pragma unroll
            for (int u = 0; u < 4; ++u)
                hTout[ntbase + (size_t)(b * HH + hq * 4 + u) * 8] = (_Float16)hn[u];
        }
    }
}

// ---------------------------------------------------------------------------
// Kernel 3c: weight prep. Whr[k][h][g] = Wh[k][g*32+h]; Wxr[c][h][g]; bfold.
// ---------------------------------------------------------------------------
__global__ __launch_bounds__(256) void prep_weights(const float* __restrict__ Wx,
                                                    const float* __restrict__ bx,
                                                    const float* __restrict__ Wh,
                                                    const float* __restrict__ bh,
                                                    float* __restrict__ Whr,
                                                    float* __restrict__ Wxr,
                                                    float* __restrict__ bfold) {
    const int tid = threadIdx.x;
#pragma unroll
    for (int r = 0; r < 16; ++r) {
        const int idx = tid * 16 + r;           // 4096
        const int k = idx >> 7, rem = idx & 127;
        const int h = rem >> 2, g = rem & 3;
        Whr[idx] = Wh[k * GC + g * HH + h];
    }
    {
        const int idx = tid;                    // 256
        const int c = idx >> 7, rem = idx & 127;
        const int h = rem >> 2, g = rem & 3;
        Wxr[idx] = Wx[c * GC + g * HH + h];
    }
    if (tid < 128) {
        const int h = tid >> 2, g = tid & 3;
        bfold[tid] = bx[g * HH + h] + bh[g * HH + h];
    }
}

// ---------------------------------------------------------------------------
// Kernel 4: t=0 gate update only (no recurrent term), 64 nodes x 4 batches.
// ---------------------------------------------------------------------------
__global__ __launch_bounds__(256) void gate_update(const float* __restrict__ AX,
                                                   const float* __restrict__ Whr,
                                                   const float* __restrict__ Wxr,
                                                   const float* __restrict__ bfold,
                                                   float* __restrict__ c,
                                                   float* __restrict__ h32,
                                                   _Float16* __restrict__ hT) {
    const int n0 = blockIdx.x * 64;
    const int b0 = blockIdx.y * 4;
    const int tid = threadIdx.x;
    __shared__ float wxr[256];
    __shared__ float bfl[128];
    __shared__ float axs[2][64];

    if (tid < 64)  *(float4*)&wxr[tid * 4] = *(const float4*)&Wxr[tid * 4];
    if (tid < 32)  *(float4*)&bfl[tid * 4] = *(const float4*)&bfold[tid * 4];

    const int nl = tid & 63;
    const int hq = tid >> 6;

    const int nd = n0 + nl;
    const size_t ntbase = ((size_t)((nd >> 5) * 4 + ((nd >> 3) & 3)) * 1024) * 8 + (nd & 7);

#pragma unroll 1
    for (int bi = 0; bi < 4; ++bi) {
        const int b = b0 + bi;
        if (bi) __syncthreads();
        if (tid < 128) {
            const int which = tid >> 6, nls = tid & 63;
            axs[which][nls] = AX[(size_t)(n0 + nls) * XCOLS + (b * TT + 0) * CIN + which];
        }
        __syncthreads();

        const float ax0 = axs[0][nl], ax1 = axs[1][nl];
        float cn[8], hn[8];
#pragma unroll
        for (int u = 0; u < 8; ++u) {
            const int h = hq * 8 + u;
            float a0 = bfl[h * 4 + 0] + ax0 * wxr[h * 4 + 0] + ax1 * wxr[128 + h * 4 + 0];
            float a1 = bfl[h * 4 + 1] + ax0 * wxr[h * 4 + 1] + ax1 * wxr[128 + h * 4 + 1];
            float a2 = bfl[h * 4 + 2] + ax0 * wxr[h * 4 + 2] + ax1 * wxr[128 + h * 4 + 2];
            float a3 = bfl[h * 4 + 3] + ax0 * wxr[h * 4 + 3] + ax1 * wxr[128 + h * 4 + 3];
            const float i_ = 1.0f / (1.0f + expf(-a0));
            const float f_ = 1.0f / (1.0f + expf(-a1));
            const float o_ = 1.0f / (1.0f + expf(-a2));
            const float g_ = tanhf(a3);
            const float ct = i_ * g_;          // c_old = 0
            (void)f_;
            cn[u] = ct;
            hn[u] = o_ * tanhf(ct);
        }
        const size_t off = (size_t)nd * HCOLS + b * HH + hq * 8;
        *(float4*)(c + off)       = make_float4(cn[0], cn[1], cn[2], cn[3]);
        *(float4*)(c + off + 4)   = make_float4(cn[4], cn[5], cn[6], cn[7]);
        *(float4*)(h32 + off)     = make_float4(hn[0], hn[1], hn[2], hn[3]);
        *(float4*)(h32 + off + 4) = make_float4(hn[4], hn[5], hn[6], hn[7]);
#pragma unroll
        for (int u = 0; u < 8; ++u)
            hT[ntbase + (size_t)(b * HH + hq * 8 + u) * 8] = (_Float16)hn[u];
    }
}

// ---------------------------------------------------------------------------
// Kernel 5: out[b][th][n] = bp[th] + sum_k h[n][b*H+k] * Wp[k][th]
// ---------------------------------------------------------------------------
__global__ __launch_bounds__(256) void head_kernel(const float* __restrict__ h,
                                                   const float* __restrict__ Wp,
                                                   const float* __restrict__ bp,
                                                   float* __restrict__ out) {
    const int idx = blockIdx.x * 256 + threadIdx.x;
    const int b = idx >> 11;
    const int n = idx & (NN - 1);
    float hv[HH];
    const float* hp = h + (size_t)n * HCOLS + b * HH;
#pragma unroll
    for (int k = 0; k < HH; ++k) hv[k] = hp[k];
#pragma unroll
    for (int th = 0; th < HOR; ++th) {
        float acc = bp[th];
#pragma unroll
        for (int k = 0; k < HH; ++k) acc += hv[k] * Wp[k * HOR + th];
        out[((size_t)b * HOR + th) * NN + n] = acc;
    }
}

// ---------------------------------------------------------------------------
extern "C" void kernel_launch(void* const* d_in, const int* in_sizes, int n_in,
                              void* d_out, int out_size, void* d_ws, size_t ws_size,
                              hipStream_t stream) {
    const float* x  = (const float*)d_in[0];
    const float* E1 = (const float*)d_in[1];
    const float* E2 = (const float*)d_in[2];
    const float* Wx = (const float*)d_in[3];
    const float* bx = (const float*)d_in[4];
    const float* Wh = (const float*)d_in[5];
    const float* bh = (const float*)d_in[6];
    const float* Wp = (const float*)d_in[7];
    const float* bp = (const float*)d_in[8];

    char* ws = (char*)d_ws;
    _Float16* A2  = (_Float16*)(ws);                    //  8 MB  tiled A
    _Float16* B2x = (_Float16*)(ws + ( 8ull << 20));    //  8 MB  tiled x hi/lo
    _Float16* hT0 = (_Float16*)(ws + (16ull << 20));    //  4 MB  tiled h (ping)
    _Float16* hT1 = (_Float16*)(ws + (20ull << 20));    //  4 MB  tiled h (pong)
    float* AX   = (float*)(ws + (24ull << 20));         //  8 MB
    float* cst  = (float*)(ws + (32ull << 20));         //  8 MB
    float* h32  = (float*)(ws + (40ull << 20));         //  8 MB
    float* Whr  = (float*)(ws + (48ull << 20));         // 16 KB
    float* Wxr  = (float*)(ws + (48ull << 20) + 65536);
    float* bfold= (float*)(ws + (48ull << 20) + 131072);
    _Float16* hTb[2] = {hT0, hT1};

    adj_softmax<<<NN, 256, 0, stream>>>(E1, E2, A2);
    transpose_x<<<(XCOLS * NN) / 256, 256, 0, stream>>>(x, B2x);
    prep_weights<<<1, 256, 0, stream>>>(Wx, bx, Wh, bh, Whr, Wxr, bfold);

    // x path: AX = A*Xhi + A*Xlo, written directly (no partials)
    gemm_fused<2, 0><<<512, 256, 0, stream>>>(A2, B2x, AX, nullptr, nullptr, nullptr,
                                              nullptr, nullptr, nullptr, nullptr, 0, 0);

    // t = 0: gates from AX only
    gate_update<<<dim3(NN / 64, BB / 4), 256, 0, stream>>>(AX, Whr, Wxr, bfold,
                                                           cst, h32, hTb[0]);
    // t = 1..15: fused GEMM + gate epilogue; hT ping-pong (read prev, write cur)
    for (int t = 1; t < TT; ++t) {
        gemm_fused<1, 1><<<512, 256, 0, stream>>>(A2, hTb[(t + 1) & 1], nullptr, AX,
                                                  Whr, Wxr, bfold, cst, h32,
                                                  hTb[t & 1], t, t == TT - 1 ? 1 : 0);
    }

    head_kernel<<<(BB * NN) / 256, 256, 0, stream>>>(h32, Wp, bp, (float*)d_out);
}

// Round 7
// 689.266 us; speedup vs baseline: 1.2853x; 1.0097x over previous
//
#include <hip/hip_runtime.h>
#include <hip/hip_bf16.h>
#include <cstddef>
#include <cstdint>

#define NN 2048      // nodes (M and K of the big GEMMs)
#define CIN 2
#define HH 32        // hidden
#define EMB 16
#define HOR 12
#define BB 32        // batch
#define TT 16        // time steps
#define GC 128       // 4*HH gate channels
#define XCOLS 1024   // B*T*C
#define HCOLS 1024   // B*H  (GEMM N dim)

// Tiled fp16 operand layouts (32-k tiles, 8-elem chunks), matching the GEMM's
// LDS layout exactly so staging is a LINEAR contiguous copy (and therefore
// directly expressible as global_load_lds: uniform LDS base + lane*16):
//   A2t [tt=64][ko=4][row=2048][e=8] : elem ((tt*4+ko)*2048+row)*8+e = A[row][tt*32+ko*8+e]
//   hTt [tt=64][ko=4][col=1024][e=8] : elem ((tt*4+ko)*1024+col)*8+e = h[node=tt*32+ko*8+e][col]
//   B2xt: hi plane same shape as hTt; lo plane at +LOPLANE elements.
#define ATILE_STRIDE 65536   // 4*2048*8 elements per 32-k tile of A
#define BTILE_STRIDE 32768   // 4*1024*8 elements per 32-k tile of B
#define LOPLANE 2097152      // elements per x plane (64*4*1024*8)

typedef __attribute__((ext_vector_type(8))) _Float16 f16x8;
typedef __attribute__((ext_vector_type(16))) float f32x16;

__device__ __forceinline__ void load_lds16(const void* g, void* l) {
    __builtin_amdgcn_global_load_lds(
        (const __attribute__((address_space(1))) void*)g,
        (__attribute__((address_space(3))) void*)l, 16, 0, 0);
}

// ---------------------------------------------------------------------------
// Kernel 1: A = softmax(relu(E1 @ E2^T)) -> A2t tiled fp16
// ---------------------------------------------------------------------------
__global__ __launch_bounds__(256) void adj_softmax(const float* __restrict__ E1,
                                                   const float* __restrict__ E2,
                                                   _Float16* __restrict__ A2) {
    const int i = blockIdx.x;
    __shared__ float red[256];
    float e1[EMB];
#pragma unroll
    for (int k = 0; k < EMB; ++k) e1[k] = E1[i * EMB + k];

    float s[8];
    float mx = -1e30f;
#pragma unroll
    for (int q = 0; q < 8; ++q) {
        const int j = q * 256 + threadIdx.x;
        float d = 0.f;
#pragma unroll
        for (int k = 0; k < EMB; ++k) d += e1[k] * E2[j * EMB + k];
        d = fmaxf(d, 0.0f);
        s[q] = d;
        mx = fmaxf(mx, d);
    }
    red[threadIdx.x] = mx;
    __syncthreads();
    for (int off = 128; off > 0; off >>= 1) {
        if (threadIdx.x < off) red[threadIdx.x] = fmaxf(red[threadIdx.x], red[threadIdx.x + off]);
        __syncthreads();
    }
    mx = red[0];
    __syncthreads();

    float sum = 0.f;
#pragma unroll
    for (int q = 0; q < 8; ++q) { s[q] = expf(s[q] - mx); sum += s[q]; }
    red[threadIdx.x] = sum;
    __syncthreads();
    for (int off = 128; off > 0; off >>= 1) {
        if (threadIdx.x < off) red[threadIdx.x] += red[threadIdx.x + off];
        __syncthreads();
    }
    const float inv = 1.0f / red[0];
#pragma unroll
    for (int q = 0; q < 8; ++q) {
        const int j  = q * 256 + threadIdx.x;      // k-index of A row i
        const int tt = j >> 5, ko = (j >> 3) & 3, e = j & 7;
        A2[((size_t)(tt * 4 + ko) * 2048 + i) * 8 + e] = (_Float16)(s[q] * inv);
    }
}

// ---------------------------------------------------------------------------
// Kernel 2: x -> B2xt tiled hi/lo fp16 planes (col = (b*T+t)*C + c).
// ---------------------------------------------------------------------------
__global__ __launch_bounds__(256) void transpose_x(const float* __restrict__ x,
                                                   _Float16* __restrict__ B2x) {
    const int idx = blockIdx.x * 256 + threadIdx.x;
    const int col = idx >> 11;
    const int j   = idx & (NN - 1);               // node index (gemm K dim)
    const int bt  = col >> 1;
    const int c   = col & 1;
    const float v = x[((size_t)bt * NN + j) * CIN + c];
    const _Float16 hi = (_Float16)v;
    const _Float16 lo = (_Float16)(v - (float)hi);
    const int tt = j >> 5, ko = (j >> 3) & 3, e = j & 7;
    const size_t base = ((size_t)(tt * 4 + ko) * 1024 + col) * 8 + e;
    B2x[base] = hi; B2x[base + LOPLANE] = lo;
}

// ---------------------------------------------------------------------------
// Kernel 3: fused full-K fp16 MFMA GEMM (32x32x16) + optional gate epilogue.
// GEOMETRY (round 7): tile M=64 nodes x N=128 cols, K=2048, BK=32 (NT=64).
// Grid 256 = 32 mb x 8 nb, 1 block/CU, 512 threads = 8 waves (2m x 4n),
// each wave one 32x32 acc pair (two k-chains). Halves per-CU operand
// traffic vs M=32: each block reads A 256KB + B 512KB = 768KB (was 1.28MB/CU)
// — B bytes amortized over 64 output rows instead of 32.
// PIPELINE: 6 LDS buffers, prefetch depth 3 (covers 1-block/CU jitter),
// counted vmcnt across raw s_barriers, never drained mid-loop. Per step:
//   STAGE(it+3) ; vmcnt(3c) ; s_barrier ; COMPUTE(it)
// c = per-wave DMA count (NPROD=1: waves 0-3 c=2, 4-7 c=1; NPROD=2: 3/2).
// WAR-safe: STAGE targets buf (it+3)%6 == buf(it-3), readers done 2 barriers
// ago. XCD swizzle: XCD owns 8 mb x 4 nb -> 2MB A-slab + 2MB hT-cols in L2.
// GATE=0: store C directly (AX path; NPROD=2 sums hi+lo planes into acc).
// GATE=1: epilogue computes gates = C*Whr + AX*Wxr + b, LSTM cell update,
//         writes c, tiled hT (ping-pong buffer), h32 on last step.
// ---------------------------------------------------------------------------
template <int NPROD, int GATE>
__global__ __launch_bounds__(512, 2) void gemm_fused(const _Float16* __restrict__ A2,
                                                     const _Float16* __restrict__ B2,
                                                     float* __restrict__ Cout,
                                                     const float* __restrict__ AX,
                                                     const float* __restrict__ Whr,
                                                     const float* __restrict__ Wxr,
                                                     const float* __restrict__ bfold,
                                                     float* __restrict__ cst,
                                                     float* __restrict__ h32,
                                                     _Float16* __restrict__ hTout,
                                                     int t, int last) {
    constexpr int NT     = 64;                       // K-steps (BK=32)
    constexpr int BUF    = 4096 + NPROD * 8192;      // bytes per buffer
    constexpr int NCHK   = 256 + NPROD * 512;        // 16B chunks per step
    constexpr int NG     = NCHK / 64;                // 64-chunk groups (12|20)
    constexpr int GMAX   = (NPROD == 1) ? 2 : 3;     // groups per wave
    constexpr int STAGE_SZ = 6 * BUF;
    constexpr int SMEMSZ = GATE ? (STAGE_SZ + 16384 + 1024 + 512 + 2048) : STAGE_SZ;
    __shared__ __align__(16) char smem[SMEMSZ];

    const int tid  = threadIdx.x;
    const int w    = tid >> 6;
    const int lane = tid & 63;

    // XCD-aware decomposition: physical XCD = wg & 7 (round-robin dispatch).
    // XCD owns 8 consecutive mb x 4 consecutive nb.
    const int wg = blockIdx.x;
    const int x8 = wg & 7;
    const int s  = wg >> 3;                 // 0..31 slot within XCD
    const int mb = (x8 >> 1) * 8 + (s & 7);
    const int nb = (x8 & 1) * 4 + (s >> 3);
    const int m0 = mb * 64;
    const int n0 = nb * 128;

    float* whr_s = nullptr; float* wxr_s = nullptr; float* bfl_s = nullptr; float* axs = nullptr;
    if constexpr (GATE) {
        whr_s = (float*)(smem + STAGE_SZ);
        wxr_s = whr_s + 4096;
        bfl_s = wxr_s + 256;
        axs   = bfl_s + 128;           // [bi 4][which 2][nl 64]
        const int b0c = nb * 4;
#pragma unroll
        for (int r = 0; r < 2; ++r)
            *(float4*)&whr_s[tid * 4 + r * 2048] = *(const float4*)&Whr[tid * 4 + r * 2048];
        if (tid < 64) *(float4*)&wxr_s[tid * 4] = *(const float4*)&Wxr[tid * 4];
        if (tid < 32) *(float4*)&bfl_s[tid * 4] = *(const float4*)&bfold[tid * 4];
        axs[tid] = AX[(size_t)(m0 + (tid & 63)) * XCOLS +
                      ((b0c + (tid >> 7)) * TT + t) * CIN + ((tid >> 6) & 1)];
    }

    // ---- per-wave staging groups. Group g covers chunks [g*64, g*64+64):
    //   cid <  256: A chunk (ko=cid>>6, row=cid&63), LDS off = cid*16
    //   cid >= 256: B chunk r2=cid-256 (plane=r2>>9, ko=(r2&511)>>7,
    //               col=r2&127), LDS off = 4096 + r2*16
    // Region boundaries (256, 768) are multiples of 64 -> no straddle.
    const _Float16* gp[GMAX];
    int lbase[GMAX];
    int adv[GMAX];
    bool val[GMAX];
#pragma unroll
    for (int i = 0; i < GMAX; ++i) {
        const int g = w + 8 * i;
        val[i] = (g < NG);
        const int gg = val[i] ? g : 0;
        const int cid  = gg * 64 + lane;
        const int cid0 = gg * 64;
        if (cid < 256) {
            gp[i]  = A2 + ((size_t)((cid >> 6) * 2048) + m0 + (cid & 63)) * 8;
            adv[i] = ATILE_STRIDE;
        } else {
            const int r2 = cid - 256;
            gp[i]  = B2 + (size_t)(r2 >> 9) * LOPLANE
                        + ((size_t)(((r2 & 511) >> 7) * 1024) + n0 + (r2 & 127)) * 8;
            adv[i] = BTILE_STRIDE;
        }
        lbase[i] = (cid0 < 256) ? cid0 * 16 : 4096 + (cid0 - 256) * 16;
    }

    // ---- fragment offsets: 8 waves = (mi = w>>2) x (nq = w&3).
    const int lrow = lane & 31, lg = lane >> 5;
    const int mi = w >> 2;
    const int wc = (w & 3) * 32;
    const int aoff0 = lg * 1024 + (mi * 32 + lrow) * 16;           // ks=0
    const int aoff1 = 2048 + lg * 1024 + (mi * 32 + lrow) * 16;    // ks=1
    const int boff0 = 4096 + lg * 2048 + (wc + lrow) * 16;
    const int boff1 = 4096 + 4096 + lg * 2048 + (wc + lrow) * 16;

    f32x16 acc0 = (f32x16)(0.0f), acc1 = (f32x16)(0.0f);

#define STAGE(BUFI) do {                                                       \
    char* lb = smem + (BUFI) * BUF;                                            \
    _Pragma("unroll")                                                          \
    for (int i = 0; i < GMAX; ++i) if (val[i]) {                               \
        load_lds16(gp[i], lb + lbase[i]);                                      \
        gp[i] += adv[i];                                                       \
    }                                                                          \
} while (0)

// counted vmcnt: wave-uniform branch picks the literal for this wave's c.
#define VMW(NHI, NLO) do {                                                     \
    if (w < 4) asm volatile("s_waitcnt vmcnt(" #NHI ")" ::: "memory");         \
    else       asm volatile("s_waitcnt vmcnt(" #NLO ")" ::: "memory");         \
} while (0)

#define BAR() do {                                                             \
    __builtin_amdgcn_s_barrier();                                              \
    asm volatile("" ::: "memory");                                             \
} while (0)

#define COMPUTE(BUFI) do {                                                     \
    const char* st = smem + (BUFI) * BUF;                                      \
    f16x8 fa0 = *(const f16x8*)(st + aoff0);                                   \
    f16x8 fa1 = *(const f16x8*)(st + aoff1);                                   \
    f16x8 fb0 = *(const f16x8*)(st + boff0);                                   \
    f16x8 fb1 = *(const f16x8*)(st + boff1);                                   \
    acc0 = __builtin_amdgcn_mfma_f32_32x32x16_f16(fa0, fb0, acc0, 0, 0, 0);    \
    acc1 = __builtin_amdgcn_mfma_f32_32x32x16_f16(fa1, fb1, acc1, 0, 0, 0);    \
    if constexpr (NPROD == 2) {                                                \
        f16x8 fc0 = *(const f16x8*)(st + boff0 + 8192);                        \
        f16x8 fc1 = *(const f16x8*)(st + boff1 + 8192);                        \
        acc0 = __builtin_amdgcn_mfma_f32_32x32x16_f16(fa0, fc0, acc0, 0, 0, 0);\
        acc1 = __builtin_amdgcn_mfma_f32_32x32x16_f16(fa1, fc1, acc1, 0, 0, 0);\
    }                                                                          \
} while (0)

    STAGE(0);                      // tile 0
    STAGE(1);                      // tile 1
    STAGE(2);                      // tile 2
    {
        int bs = 3, bc = 0;        // stage / compute buffer cursors (mod 6)
#pragma unroll 1
        for (int it = 0; it < NT - 3; ++it) {
            STAGE(bs);                              // prefetch depth 3
            if constexpr (NPROD == 1) VMW(6, 3); else VMW(9, 6);
            BAR();
            COMPUTE(bc);
            bs = (bs == 5) ? 0 : bs + 1;
            bc = (bc == 5) ? 0 : bc + 1;
        }
        if constexpr (NPROD == 1) VMW(4, 2); else VMW(6, 4);
        BAR();
        COMPUTE(bc); bc = (bc == 5) ? 0 : bc + 1;
        if constexpr (NPROD == 1) VMW(2, 1); else VMW(3, 2);
        BAR();
        COMPUTE(bc); bc = (bc == 5) ? 0 : bc + 1;
        asm volatile("s_waitcnt vmcnt(0)" ::: "memory");
        BAR();
        COMPUTE(bc);
    }
#undef STAGE
#undef VMW
#undef BAR
#undef COMPUTE

    // ---- C layout per 32x32 acc: col=lane&31, row=(r&3)+8*(r>>2)+4*lg ----
    if constexpr (!GATE) {
        const int colg = n0 + wc + lrow;
#pragma unroll
        for (int r = 0; r < 16; ++r) {
            const int rp = (r & 3) + 8 * (r >> 2) + 4 * lg;
            Cout[(size_t)(m0 + mi * 32 + rp) * XCOLS + colg] = acc0[r] + acc1[r];
        }
    } else {
        // stage Ah tile to LDS for the node-major gate pass. ah = 33KB spans
        // bufs 0-2 (<36864); final COMPUTE read buf 3 (36864+) -> disjoint.
        float* ah = (float*)smem;               // [64][129]
#pragma unroll
        for (int r = 0; r < 16; ++r) {
            const int rp = (r & 3) + 8 * (r >> 2) + 4 * lg;
            ah[(mi * 32 + rp) * 129 + wc + lrow] = acc0[r] + acc1[r];
        }
        __syncthreads();

        const int nl2 = tid & 63;               // node within tile (64)
        const int hq  = tid >> 6;               // 0..7 -> h = hq*4+u
        const int b0c = nb * 4;
        const int nd  = m0 + nl2;
        const size_t ntbase = ((size_t)((nd >> 5) * 4 + ((nd >> 3) & 3)) * 1024) * 8 + (nd & 7);

#pragma unroll 1
        for (int bi = 0; bi < 4; ++bi) {
            const float ax0 = axs[bi * 128 + nl2];
            const float ax1 = axs[bi * 128 + 64 + nl2];
            float ar[32];
#pragma unroll
            for (int k = 0; k < 32; ++k) ar[k] = ah[nl2 * 129 + bi * 32 + k];

            float a4[4][4];
#pragma unroll
            for (int u = 0; u < 4; ++u) {
                const int h = hq * 4 + u;
#pragma unroll
                for (int g = 0; g < 4; ++g)
                    a4[u][g] = bfl_s[h * 4 + g] + ax0 * wxr_s[h * 4 + g] + ax1 * wxr_s[128 + h * 4 + g];
            }
#pragma unroll 4
            for (int k = 0; k < 32; ++k) {
                const float av = ar[k];
#pragma unroll
                for (int u = 0; u < 4; ++u) {
                    const float* wp = &whr_s[(k * 32 + hq * 4 + u) * 4];
                    a4[u][0] += av * wp[0];
                    a4[u][1] += av * wp[1];
                    a4[u][2] += av * wp[2];
                    a4[u][3] += av * wp[3];
                }
            }

            const int b = b0c + bi;
            const size_t off = (size_t)nd * HCOLS + b * HH + hq * 4;
            const float4 co = *(const float4*)(cst + off);
            const float cold[4] = {co.x, co.y, co.z, co.w};
            float cn[4], hn[4];
#pragma unroll
            for (int u = 0; u < 4; ++u) {
                const float i_ = 1.0f / (1.0f + expf(-a4[u][0]));
                const float f_ = 1.0f / (1.0f + expf(-a4[u][1]));
                const float o_ = 1.0f / (1.0f + expf(-a4[u][2]));
                const float g_ = tanhf(a4[u][3]);
                const float ct = f_ * cold[u] + i_ * g_;
                cn[u] = ct;
                hn[u] = o_ * tanhf(ct);
            }
            *(float4*)(cst + off) = make_float4(cn[0], cn[1], cn[2], cn[3]);
            if (last) *(float4*)(h32 + off) = make_float4(hn[0], hn[1], hn[2], hn[3]);
#pragma unroll
            for (int u = 0; u < 4; ++u)
                hTout[ntbase + (size_t)(b * HH + hq * 4 + u) * 8] = (_Float16)hn[u];
        }
    }
}

// ---------------------------------------------------------------------------
// Kernel 3c: weight prep. Whr[k][h][g] = Wh[k][g*32+h]; Wxr[c][h][g]; bfold.
// ---------------------------------------------------------------------------
__global__ __launch_bounds__(256) void prep_weights(const float* __restrict__ Wx,
                                                    const float* __restrict__ bx,
                                                    const float* __restrict__ Wh,
                                                    const float* __restrict__ bh,
                                                    float* __restrict__ Whr,
                                                    float* __restrict__ Wxr,
                                                    float* __restrict__ bfold) {
    const int tid = threadIdx.x;
#pragma unroll
    for (int r = 0; r < 16; ++r) {
        const int idx = tid * 16 + r;           // 4096
        const int k = idx >> 7, rem = idx & 127;
        const int h = rem >> 2, g = rem & 3;
        Whr[idx] = Wh[k * GC + g * HH + h];
    }
    {
        const int idx = tid;                    // 256
        const int c = idx >> 7, rem = idx & 127;
        const int h = rem >> 2, g = rem & 3;
        Wxr[idx] = Wx[c * GC + g * HH + h];
    }
    if (tid < 128) {
        const int h = tid >> 2, g = tid & 3;
        bfold[tid] = bx[g * HH + h] + bh[g * HH + h];
    }
}

// ---------------------------------------------------------------------------
// Kernel 4: t=0 gate update only (no recurrent term), 64 nodes x 4 batches.
// ---------------------------------------------------------------------------
__global__ __launch_bounds__(256) void gate_update(const float* __restrict__ AX,
                                                   const float* __restrict__ Whr,
                                                   const float* __restrict__ Wxr,
                                                   const float* __restrict__ bfold,
                                                   float* __restrict__ c,
                                                   float* __restrict__ h32,
                                                   _Float16* __restrict__ hT) {
    const int n0 = blockIdx.x * 64;
    const int b0 = blockIdx.y * 4;
    const int tid = threadIdx.x;
    __shared__ float wxr[256];
    __shared__ float bfl[128];
    __shared__ float axs[2][64];

    if (tid < 64)  *(float4*)&wxr[tid * 4] = *(const float4*)&Wxr[tid * 4];
    if (tid < 32)  *(float4*)&bfl[tid * 4] = *(const float4*)&bfold[tid * 4];

    const int nl = tid & 63;
    const int hq = tid >> 6;

    const int nd = n0 + nl;
    const size_t ntbase = ((size_t)((nd >> 5) * 4 + ((nd >> 3) & 3)) * 1024) * 8 + (nd & 7);

#pragma unroll 1
    for (int bi = 0; bi < 4; ++bi) {
        const int b = b0 + bi;
        if (bi) __syncthreads();
        if (tid < 128) {
            const int which = tid >> 6, nls = tid & 63;
            axs[which][nls] = AX[(size_t)(n0 + nls) * XCOLS + (b * TT + 0) * CIN + which];
        }
        __syncthreads();

        const float ax0 = axs[0][nl], ax1 = axs[1][nl];
        float cn[8], hn[8];
#pragma unroll
        for (int u = 0; u < 8; ++u) {
            const int h = hq * 8 + u;
            float a0 = bfl[h * 4 + 0] + ax0 * wxr[h * 4 + 0] + ax1 * wxr[128 + h * 4 + 0];
            float a1 = bfl[h * 4 + 1] + ax0 * wxr[h * 4 + 1] + ax1 * wxr[128 + h * 4 + 1];
            float a2 = bfl[h * 4 + 2] + ax0 * wxr[h * 4 + 2] + ax1 * wxr[128 + h * 4 + 2];
            float a3 = bfl[h * 4 + 3] + ax0 * wxr[h * 4 + 3] + ax1 * wxr[128 + h * 4 + 3];
            const float i_ = 1.0f / (1.0f + expf(-a0));
            const float f_ = 1.0f / (1.0f + expf(-a1));
            const float o_ = 1.0f / (1.0f + expf(-a2));
            const float g_ = tanhf(a3);
            const float ct = i_ * g_;          // c_old = 0
            (void)f_;
            cn[u] = ct;
            hn[u] = o_ * tanhf(ct);
        }
        const size_t off = (size_t)nd * HCOLS + b * HH + hq * 8;
        *(float4*)(c + off)       = make_float4(cn[0], cn[1], cn[2], cn[3]);
        *(float4*)(c + off + 4)   = make_float4(cn[4], cn[5], cn[6], cn[7]);
        *(float4*)(h32 + off)     = make_float4(hn[0], hn[1], hn[2], hn[3]);
        *(float4*)(h32 + off + 4) = make_float4(hn[4], hn[5], hn[6], hn[7]);
#pragma unroll
        for (int u = 0; u < 8; ++u)
            hT[ntbase + (size_t)(b * HH + hq * 8 + u) * 8] = (_Float16)hn[u];
    }
}

// ---------------------------------------------------------------------------
// Kernel 5: out[b][th][n] = bp[th] + sum_k h[n][b*H+k] * Wp[k][th]
// ---------------------------------------------------------------------------
__global__ __launch_bounds__(256) void head_kernel(const float* __restrict__ h,
                                                   const float* __restrict__ Wp,
                                                   const float* __restrict__ bp,
                                                   float* __restrict__ out) {
    const int idx = blockIdx.x * 256 + threadIdx.x;
    const int b = idx >> 11;
    const int n = idx & (NN - 1);
    float hv[HH];
    const float* hp = h + (size_t)n * HCOLS + b * HH;
#pragma unroll
    for (int k = 0; k < HH; ++k) hv[k] = hp[k];
#pragma unroll
    for (int th = 0; th < HOR; ++th) {
        float acc = bp[th];
#pragma unroll
        for (int k = 0; k < HH; ++k) acc += hv[k] * Wp[k * HOR + th];
        out[((size_t)b * HOR + th) * NN + n] = acc;
    }
}

// ---------------------------------------------------------------------------
extern "C" void kernel_launch(void* const* d_in, const int* in_sizes, int n_in,
                              void* d_out, int out_size, void* d_ws, size_t ws_size,
                              hipStream_t stream) {
    const float* x  = (const float*)d_in[0];
    const float* E1 = (const float*)d_in[1];
    const float* E2 = (const float*)d_in[2];
    const float* Wx = (const float*)d_in[3];
    const float* bx = (const float*)d_in[4];
    const float* Wh = (const float*)d_in[5];
    const float* bh = (const float*)d_in[6];
    const float* Wp = (const float*)d_in[7];
    const float* bp = (const float*)d_in[8];

    char* ws = (char*)d_ws;
    _Float16* A2  = (_Float16*)(ws);                    //  8 MB  tiled A
    _Float16* B2x = (_Float16*)(ws + ( 8ull << 20));    //  8 MB  tiled x hi/lo
    _Float16* hT0 = (_Float16*)(ws + (16ull << 20));    //  4 MB  tiled h (ping)
    _Float16* hT1 = (_Float16*)(ws + (20ull << 20));    //  4 MB  tiled h (pong)
    float* AX   = (float*)(ws + (24ull << 20));         //  8 MB
    float* cst  = (float*)(ws + (32ull << 20));         //  8 MB
    float* h32  = (float*)(ws + (40ull << 20));         //  8 MB
    float* Whr  = (float*)(ws + (48ull << 20));         // 16 KB
    float* Wxr  = (float*)(ws + (48ull << 20) + 65536);
    float* bfold= (float*)(ws + (48ull << 20) + 131072);
    _Float16* hTb[2] = {hT0, hT1};

    adj_softmax<<<NN, 256, 0, stream>>>(E1, E2, A2);
    transpose_x<<<(XCOLS * NN) / 256, 256, 0, stream>>>(x, B2x);
    prep_weights<<<1, 256, 0, stream>>>(Wx, bx, Wh, bh, Whr, Wxr, bfold);

    // x path: AX = A*Xhi + A*Xlo, written directly (no partials)
    gemm_fused<2, 0><<<256, 512, 0, stream>>>(A2, B2x, AX, nullptr, nullptr, nullptr,
                                              nullptr, nullptr, nullptr, nullptr, 0, 0);

    // t = 0: gates from AX only
    gate_update<<<dim3(NN / 64, BB / 4), 256, 0, stream>>>(AX, Whr, Wxr, bfold,
                                                           cst, h32, hTb[0]);
    // t = 1..15: fused GEMM + gate epilogue; hT ping-pong (read prev, write cur)
    for (int t = 1; t < TT; ++t) {
        gemm_fused<1, 1><<<256, 512, 0, stream>>>(A2, hTb[(t + 1) & 1], nullptr, AX,
                                                  Whr, Wxr, bfold, cst, h32,
                                                  hTb[t & 1], t, t == TT - 1 ? 1 : 0);
    }

    head_kernel<<<(BB * NN) / 256, 256, 0, stream>>>(h32, Wp, bp, (float*)d_out);
}

// Round 8
// 609.906 us; speedup vs baseline: 1.4526x; 1.1301x over previous
//
#include <hip/hip_runtime.h>
#include <hip/hip_bf16.h>
#include <cstddef>
#include <cstdint>

#define NN 2048      // nodes (M and K of the big GEMMs)
#define CIN 2
#define HH 32        // hidden
#define EMB 16
#define HOR 12
#define BB 32        // batch
#define TT 16        // time steps
#define GC 128       // 4*HH gate channels
#define XCOLS 1024   // B*T*C
#define HCOLS 1024   // B*H  (GEMM N dim)

// Tiled fp16 operand layouts (32-k tiles, 8-elem chunks), matching the GEMM's
// LDS layout exactly so staging is a LINEAR contiguous copy (and therefore
// directly expressible as global_load_lds: uniform LDS base + lane*16):
//   A2t [tt=64][ko=4][row=2048][e=8] : elem ((tt*4+ko)*2048+row)*8+e = A[row][tt*32+ko*8+e]
//   hTt [tt=64][ko=4][col=1024][e=8] : elem ((tt*4+ko)*1024+col)*8+e = h[node=tt*32+ko*8+e][col]
//   B2xt: hi plane same shape as hTt; lo plane at +LOPLANE elements.
#define ATILE_STRIDE 65536   // 4*2048*8 elements per 32-k tile of A
#define BTILE_STRIDE 32768   // 4*1024*8 elements per 32-k tile of B
#define LOPLANE 2097152      // elements per x plane (64*4*1024*8)

typedef __attribute__((ext_vector_type(8))) _Float16 f16x8;
typedef __attribute__((ext_vector_type(16))) float f32x16;

__device__ __forceinline__ void load_lds16(const void* g, void* l) {
    __builtin_amdgcn_global_load_lds(
        (const __attribute__((address_space(1))) void*)g,
        (__attribute__((address_space(3))) void*)l, 16, 0, 0);
}

// ---------------------------------------------------------------------------
// Kernel 1: A = softmax(relu(E1 @ E2^T)) -> A2t tiled fp16
// ---------------------------------------------------------------------------
__global__ __launch_bounds__(256) void adj_softmax(const float* __restrict__ E1,
                                                   const float* __restrict__ E2,
                                                   _Float16* __restrict__ A2) {
    const int i = blockIdx.x;
    __shared__ float red[256];
    float e1[EMB];
#pragma unroll
    for (int k = 0; k < EMB; ++k) e1[k] = E1[i * EMB + k];

    float s[8];
    float mx = -1e30f;
#pragma unroll
    for (int q = 0; q < 8; ++q) {
        const int j = q * 256 + threadIdx.x;
        float d = 0.f;
#pragma unroll
        for (int k = 0; k < EMB; ++k) d += e1[k] * E2[j * EMB + k];
        d = fmaxf(d, 0.0f);
        s[q] = d;
        mx = fmaxf(mx, d);
    }
    red[threadIdx.x] = mx;
    __syncthreads();
    for (int off = 128; off > 0; off >>= 1) {
        if (threadIdx.x < off) red[threadIdx.x] = fmaxf(red[threadIdx.x], red[threadIdx.x + off]);
        __syncthreads();
    }
    mx = red[0];
    __syncthreads();

    float sum = 0.f;
#pragma unroll
    for (int q = 0; q < 8; ++q) { s[q] = expf(s[q] - mx); sum += s[q]; }
    red[threadIdx.x] = sum;
    __syncthreads();
    for (int off = 128; off > 0; off >>= 1) {
        if (threadIdx.x < off) red[threadIdx.x] += red[threadIdx.x + off];
        __syncthreads();
    }
    const float inv = 1.0f / red[0];
#pragma unroll
    for (int q = 0; q < 8; ++q) {
        const int j  = q * 256 + threadIdx.x;      // k-index of A row i
        const int tt = j >> 5, ko = (j >> 3) & 3, e = j & 7;
        A2[((size_t)(tt * 4 + ko) * 2048 + i) * 8 + e] = (_Float16)(s[q] * inv);
    }
}

// ---------------------------------------------------------------------------
// Kernel 2: x -> B2xt tiled hi/lo fp16 planes (col = (b*T+t)*C + c).
// ---------------------------------------------------------------------------
__global__ __launch_bounds__(256) void transpose_x(const float* __restrict__ x,
                                                   _Float16* __restrict__ B2x) {
    const int idx = blockIdx.x * 256 + threadIdx.x;
    const int col = idx >> 11;
    const int j   = idx & (NN - 1);               // node index (gemm K dim)
    const int bt  = col >> 1;
    const int c   = col & 1;
    const float v = x[((size_t)bt * NN + j) * CIN + c];
    const _Float16 hi = (_Float16)v;
    const _Float16 lo = (_Float16)(v - (float)hi);
    const int tt = j >> 5, ko = (j >> 3) & 3, e = j & 7;
    const size_t base = ((size_t)(tt * 4 + ko) * 1024 + col) * 8 + e;
    B2x[base] = hi; B2x[base + LOPLANE] = lo;
}

// ---------------------------------------------------------------------------
// Kernel 3: fused full-K fp16 MFMA GEMM (32x32x16) + MFMA gate epilogue.
// Tile M=64 x N=128, K=2048, BK=32 (NT=64). Grid 256, 1 block/CU, 8 waves.
// K-loop: identical to round 7 (DMA staging, 6 bufs, depth-3 counted vmcnt).
// GATE epilogue (round 8 — replaces the VALU gate-GEMM):
//   gates[64n x 4b x 128ch] = Ah @ Wh is itself a GEMM (K=32) -> use MFMA.
//   Precision via hi/lo fp16 split of BOTH operands (validated by the x path):
//   gates ~= Ahi*Whi + Ahi*Wlo + Alo*Whi  (dropped Alo*Wlo ~1e-7 rel).
//   acc -> LDS hi/lo fp16 planes [64][136]; Wh pre-split into MFMA B-frag
//   tables (W16, 2x8KB, L2-resident, loaded AFTER the K-loop so the counted
//   vmcnt discipline is undisturbed). 24 MFMAs/wave replace ~2048 VALU FMAs
//   + 512 LDS broadcasts per thread. Then per-b: gate tile -> LDS f32
//   [64][132] so each thread reads its 4 gates as one float4; sigmoid/tanh/
//   cell update unchanged; writes c, tiled hT, h32 on last step.
// ---------------------------------------------------------------------------
template <int NPROD, int GATE>
__global__ __launch_bounds__(512, 2) void gemm_fused(const _Float16* __restrict__ A2,
                                                     const _Float16* __restrict__ B2,
                                                     float* __restrict__ Cout,
                                                     const float* __restrict__ AX,
                                                     const _Float16* __restrict__ W16,
                                                     const float* __restrict__ Wxr,
                                                     const float* __restrict__ bfold,
                                                     float* __restrict__ cst,
                                                     float* __restrict__ h32,
                                                     _Float16* __restrict__ hTout,
                                                     int t, int last) {
    constexpr int NT     = 64;                       // K-steps (BK=32)
    constexpr int BUF    = 4096 + NPROD * 8192;      // bytes per buffer
    constexpr int NCHK   = 256 + NPROD * 512;        // 16B chunks per step
    constexpr int NG     = NCHK / 64;                // 64-chunk groups (12|20)
    constexpr int GMAX   = (NPROD == 1) ? 2 : 3;     // groups per wave
    constexpr int STAGE_SZ = 6 * BUF;
    constexpr int GLSZ   = 64 * 132 * 4;             // gate staging 33792 B
    constexpr int SMEMSZ = GATE ? (STAGE_SZ + GLSZ + 1024 + 512 + 2048) : STAGE_SZ;
    __shared__ __align__(16) char smem[SMEMSZ];

    const int tid  = threadIdx.x;
    const int w    = tid >> 6;
    const int lane = tid & 63;

    // XCD-aware decomposition: physical XCD = wg & 7 (round-robin dispatch).
    const int wg = blockIdx.x;
    const int x8 = wg & 7;
    const int s  = wg >> 3;                 // 0..31 slot within XCD
    const int mb = (x8 >> 1) * 8 + (s & 7);
    const int nb = (x8 & 1) * 4 + (s >> 3);
    const int m0 = mb * 64;
    const int n0 = nb * 128;

    float* wxr_s = nullptr; float* bfl_s = nullptr; float* axs = nullptr;
    if constexpr (GATE) {
        wxr_s = (float*)(smem + STAGE_SZ + GLSZ);
        bfl_s = wxr_s + 256;
        axs   = bfl_s + 128;           // [bi 4][which 2][nl 64]
        const int b0c = nb * 4;
        if (tid < 64) *(float4*)&wxr_s[tid * 4] = *(const float4*)&Wxr[tid * 4];
        if (tid < 32) *(float4*)&bfl_s[tid * 4] = *(const float4*)&bfold[tid * 4];
        axs[tid] = AX[(size_t)(m0 + (tid & 63)) * XCOLS +
                      ((b0c + (tid >> 7)) * TT + t) * CIN + ((tid >> 6) & 1)];
    }

    // ---- per-wave staging groups (round 7, unchanged).
    const _Float16* gp[GMAX];
    int lbase[GMAX];
    int adv[GMAX];
    bool val[GMAX];
#pragma unroll
    for (int i = 0; i < GMAX; ++i) {
        const int g = w + 8 * i;
        val[i] = (g < NG);
        const int gg = val[i] ? g : 0;
        const int cid  = gg * 64 + lane;
        const int cid0 = gg * 64;
        if (cid < 256) {
            gp[i]  = A2 + ((size_t)((cid >> 6) * 2048) + m0 + (cid & 63)) * 8;
            adv[i] = ATILE_STRIDE;
        } else {
            const int r2 = cid - 256;
            gp[i]  = B2 + (size_t)(r2 >> 9) * LOPLANE
                        + ((size_t)(((r2 & 511) >> 7) * 1024) + n0 + (r2 & 127)) * 8;
            adv[i] = BTILE_STRIDE;
        }
        lbase[i] = (cid0 < 256) ? cid0 * 16 : 4096 + (cid0 - 256) * 16;
    }

    // ---- fragment offsets: 8 waves = (mi = w>>2) x (gq = w&3).
    const int lrow = lane & 31, lg = lane >> 5;
    const int mi = w >> 2;
    const int gq = w & 3;
    const int wc = gq * 32;
    const int aoff0 = lg * 1024 + (mi * 32 + lrow) * 16;           // ks=0
    const int aoff1 = 2048 + lg * 1024 + (mi * 32 + lrow) * 16;    // ks=1
    const int boff0 = 4096 + lg * 2048 + (wc + lrow) * 16;
    const int boff1 = 4096 + 4096 + lg * 2048 + (wc + lrow) * 16;

    f32x16 acc0 = (f32x16)(0.0f), acc1 = (f32x16)(0.0f);

#define STAGE(BUFI) do {                                                       \
    char* lb = smem + (BUFI) * BUF;                                            \
    _Pragma("unroll")                                                          \
    for (int i = 0; i < GMAX; ++i) if (val[i]) {                               \
        load_lds16(gp[i], lb + lbase[i]);                                      \
        gp[i] += adv[i];                                                       \
    }                                                                          \
} while (0)

#define VMW(NHI, NLO) do {                                                     \
    if (w < 4) asm volatile("s_waitcnt vmcnt(" #NHI ")" ::: "memory");         \
    else       asm volatile("s_waitcnt vmcnt(" #NLO ")" ::: "memory");         \
} while (0)

#define BAR() do {                                                             \
    __builtin_amdgcn_s_barrier();                                              \
    asm volatile("" ::: "memory");                                             \
} while (0)

#define COMPUTE(BUFI) do {                                                     \
    const char* st = smem + (BUFI) * BUF;                                      \
    f16x8 fa0 = *(const f16x8*)(st + aoff0);                                   \
    f16x8 fa1 = *(const f16x8*)(st + aoff1);                                   \
    f16x8 fb0 = *(const f16x8*)(st + boff0);                                   \
    f16x8 fb1 = *(const f16x8*)(st + boff1);                                   \
    acc0 = __builtin_amdgcn_mfma_f32_32x32x16_f16(fa0, fb0, acc0, 0, 0, 0);    \
    acc1 = __builtin_amdgcn_mfma_f32_32x32x16_f16(fa1, fb1, acc1, 0, 0, 0);    \
    if constexpr (NPROD == 2) {                                                \
        f16x8 fc0 = *(const f16x8*)(st + boff0 + 8192);                        \
        f16x8 fc1 = *(const f16x8*)(st + boff1 + 8192);                        \
        acc0 = __builtin_amdgcn_mfma_f32_32x32x16_f16(fa0, fc0, acc0, 0, 0, 0);\
        acc1 = __builtin_amdgcn_mfma_f32_32x32x16_f16(fa1, fc1, acc1, 0, 0, 0);\
    }                                                                          \
} while (0)

    STAGE(0);                      // tile 0
    STAGE(1);                      // tile 1
    STAGE(2);                      // tile 2
    {
        int bs = 3, bc = 0;        // stage / compute buffer cursors (mod 6)
#pragma unroll 1
        for (int it = 0; it < NT - 3; ++it) {
            STAGE(bs);                              // prefetch depth 3
            if constexpr (NPROD == 1) VMW(6, 3); else VMW(9, 6);
            BAR();
            COMPUTE(bc);
            bs = (bs == 5) ? 0 : bs + 1;
            bc = (bc == 5) ? 0 : bc + 1;
        }
        if constexpr (NPROD == 1) VMW(4, 2); else VMW(6, 4);
        BAR();
        COMPUTE(bc); bc = (bc == 5) ? 0 : bc + 1;
        if constexpr (NPROD == 1) VMW(2, 1); else VMW(3, 2);
        BAR();
        COMPUTE(bc); bc = (bc == 5) ? 0 : bc + 1;
        asm volatile("s_waitcnt vmcnt(0)" ::: "memory");
        BAR();
        COMPUTE(bc);               // reads buf 3 (ah planes use bufs 0-2)
    }
#undef STAGE
#undef VMW
#undef BAR
#undef COMPUTE

    // ---- C layout per 32x32 acc: col=lane&31, row=(r&3)+8*(r>>2)+4*lg ----
    if constexpr (!GATE) {
        const int colg = n0 + wc + lrow;
#pragma unroll
        for (int r = 0; r < 16; ++r) {
            const int rp = (r & 3) + 8 * (r >> 2) + 4 * lg;
            Cout[(size_t)(m0 + mi * 32 + rp) * XCOLS + colg] = acc0[r] + acc1[r];
        }
    } else {
        // -- W-frag loads (L2-resident; issued post-loop, vmcnt slate clean)
        f16x8 wbh0 = *(const f16x8*)(W16 + ((size_t)(0 * 4 + gq) * 64 + lane) * 8);
        f16x8 wbh1 = *(const f16x8*)(W16 + ((size_t)(1 * 4 + gq) * 64 + lane) * 8);
        f16x8 wbl0 = *(const f16x8*)(W16 + 8192 + ((size_t)(0 * 4 + gq) * 64 + lane) * 8);
        f16x8 wbl1 = *(const f16x8*)(W16 + 8192 + ((size_t)(1 * 4 + gq) * 64 + lane) * 8);

        // -- stage Ah as hi/lo fp16 planes [64][136] (overlays bufs 0-2)
        _Float16* ahh = (_Float16*)smem;
        _Float16* ahl = (_Float16*)(smem + 17408);
        const int colw = wc + lrow;
#pragma unroll
        for (int r = 0; r < 16; ++r) {
            const int rp = (r & 3) + 8 * (r >> 2) + 4 * lg;
            const float v = acc0[r] + acc1[r];
            const _Float16 hi = (_Float16)v;
            ahh[(mi * 32 + rp) * 136 + colw] = hi;
            ahl[(mi * 32 + rp) * 136 + colw] = (_Float16)(v - (float)hi);
        }
        __syncthreads();

        // -- gate GEMM: wave (mi, gq) computes [32n x 32ch] for each b
        f32x16 g0 = (f32x16)(0.0f), g1 = (f32x16)(0.0f);
        f32x16 g2 = (f32x16)(0.0f), g3 = (f32x16)(0.0f);
#define GATEB(ACC, b) do {                                                         \
    const int arow = (mi * 32 + lrow) * 136 + (b) * 32 + lg * 8;                   \
    f16x8 fh0 = *(const f16x8*)(ahh + arow);                                       \
    f16x8 fl0 = *(const f16x8*)(ahl + arow);                                       \
    f16x8 fh1 = *(const f16x8*)(ahh + arow + 16);                                  \
    f16x8 fl1 = *(const f16x8*)(ahl + arow + 16);                                  \
    ACC = __builtin_amdgcn_mfma_f32_32x32x16_f16(fh0, wbh0, ACC, 0, 0, 0);         \
    ACC = __builtin_amdgcn_mfma_f32_32x32x16_f16(fh0, wbl0, ACC, 0, 0, 0);         \
    ACC = __builtin_amdgcn_mfma_f32_32x32x16_f16(fl0, wbh0, ACC, 0, 0, 0);         \
    ACC = __builtin_amdgcn_mfma_f32_32x32x16_f16(fh1, wbh1, ACC, 0, 0, 0);         \
    ACC = __builtin_amdgcn_mfma_f32_32x32x16_f16(fh1, wbl1, ACC, 0, 0, 0);         \
    ACC = __builtin_amdgcn_mfma_f32_32x32x16_f16(fl1, wbh1, ACC, 0, 0, 0);         \
} while (0)
        GATEB(g0, 0); GATEB(g1, 1); GATEB(g2, 2); GATEB(g3, 3);
#undef GATEB

        // -- per-b: stage gate tile to LDS f32 [64][132]; pointwise LSTM
        float* gl = (float*)(smem + STAGE_SZ);
        const int nl2 = tid & 63;
        const int hb  = (tid >> 6) * 4;
        const int b0c = nb * 4;
        const int nd  = m0 + nl2;
        const size_t ntbase = ((size_t)((nd >> 5) * 4 + ((nd >> 3) & 3)) * 1024) * 8 + (nd & 7);

#define POINT(ACC, bi) do {                                                        \
    _Pragma("unroll")                                                              \
    for (int r = 0; r < 16; ++r) {                                                 \
        const int rp = (r & 3) + 8 * (r >> 2) + 4 * lg;                            \
        gl[(mi * 32 + rp) * 132 + gq * 32 + lrow] = ACC[r];                        \
    }                                                                              \
    __syncthreads();                                                               \
    {                                                                              \
        const float ax0 = axs[(bi) * 128 + nl2];                                   \
        const float ax1 = axs[(bi) * 128 + 64 + nl2];                              \
        const int bb = b0c + (bi);                                                 \
        const size_t off = (size_t)nd * HCOLS + bb * HH + hb;                      \
        const float4 co = *(const float4*)(cst + off);                             \
        const float cold[4] = {co.x, co.y, co.z, co.w};                            \
        float cn[4], hn[4];                                                        \
        _Pragma("unroll")                                                          \
        for (int p = 0; p < 4; ++p) {                                              \
            const int hh = hb + p;                                                 \
            const float4 gt = *(const float4*)(gl + nl2 * 132 + hh * 4);           \
            const float a0 = gt.x + bfl_s[hh*4+0] + ax0*wxr_s[hh*4+0] + ax1*wxr_s[128+hh*4+0]; \
            const float a1 = gt.y + bfl_s[hh*4+1] + ax0*wxr_s[hh*4+1] + ax1*wxr_s[128+hh*4+1]; \
            const float a2 = gt.z + bfl_s[hh*4+2] + ax0*wxr_s[hh*4+2] + ax1*wxr_s[128+hh*4+2]; \
            const float a3 = gt.w + bfl_s[hh*4+3] + ax0*wxr_s[hh*4+3] + ax1*wxr_s[128+hh*4+3]; \
            const float i_ = 1.0f / (1.0f + expf(-a0));                            \
            const float f_ = 1.0f / (1.0f + expf(-a1));                            \
            const float o_ = 1.0f / (1.0f + expf(-a2));                            \
            const float g_ = tanhf(a3);                                            \
            const float ct = f_ * cold[p] + i_ * g_;                               \
            cn[p] = ct;                                                            \
            hn[p] = o_ * tanhf(ct);                                                \
        }                                                                          \
        *(float4*)(cst + off) = make_float4(cn[0], cn[1], cn[2], cn[3]);           \
        if (last) *(float4*)(h32 + off) = make_float4(hn[0], hn[1], hn[2], hn[3]); \
        _Pragma("unroll")                                                          \
        for (int p = 0; p < 4; ++p)                                                \
            hTout[ntbase + (size_t)(bb * HH + hb + p) * 8] = (_Float16)hn[p];      \
    }                                                                              \
    __syncthreads();                                                               \
} while (0)
        POINT(g0, 0); POINT(g1, 1); POINT(g2, 2); POINT(g3, 3);
#undef POINT
    }
}

// ---------------------------------------------------------------------------
// Kernel 3c: weight prep. W16 hi/lo = Wh split into MFMA B-frag tables
// ([kh 2][gq 4][lane 64][e 8], hi at 0, lo at +8192); Wxr[c][h][g]; bfold.
// ---------------------------------------------------------------------------
__global__ __launch_bounds__(256) void prep_weights(const float* __restrict__ Wx,
                                                    const float* __restrict__ bx,
                                                    const float* __restrict__ Wh,
                                                    const float* __restrict__ bh,
                                                    _Float16* __restrict__ W16,
                                                    float* __restrict__ Wxr,
                                                    float* __restrict__ bfold) {
    const int tid = threadIdx.x;
#pragma unroll
    for (int r = 0; r < 32; ++r) {
        const int idx = r * 256 + tid;          // 8192 frag entries
        const int e  = idx & 7;
        const int ln = (idx >> 3) & 63;
        const int gq = (idx >> 9) & 3;
        const int kh = (idx >> 11) & 1;
        const int k  = kh * 16 + (ln >> 5) * 8 + e;
        const int ch = gq * 32 + (ln & 31);     // channel = h*4 + gate
        const float v = Wh[k * GC + (ch & 3) * HH + (ch >> 2)];
        const _Float16 hi = (_Float16)v;
        W16[idx] = hi;
        W16[8192 + idx] = (_Float16)(v - (float)hi);
    }
    {
        const int idx = tid;                    // 256
        const int c = idx >> 7, rem = idx & 127;
        const int h = rem >> 2, g = rem & 3;
        Wxr[idx] = Wx[c * GC + g * HH + h];
    }
    if (tid < 128) {
        const int h = tid >> 2, g = tid & 3;
        bfold[tid] = bx[g * HH + h] + bh[g * HH + h];
    }
}

// ---------------------------------------------------------------------------
// Kernel 4: t=0 gate update only (no recurrent term), 64 nodes x 4 batches.
// ---------------------------------------------------------------------------
__global__ __launch_bounds__(256) void gate_update(const float* __restrict__ AX,
                                                   const float* __restrict__ Wxr,
                                                   const float* __restrict__ bfold,
                                                   float* __restrict__ c,
                                                   float* __restrict__ h32,
                                                   _Float16* __restrict__ hT) {
    const int n0 = blockIdx.x * 64;
    const int b0 = blockIdx.y * 4;
    const int tid = threadIdx.x;
    __shared__ float wxr[256];
    __shared__ float bfl[128];
    __shared__ float axs[2][64];

    if (tid < 64)  *(float4*)&wxr[tid * 4] = *(const float4*)&Wxr[tid * 4];
    if (tid < 32)  *(float4*)&bfl[tid * 4] = *(const float4*)&bfold[tid * 4];

    const int nl = tid & 63;
    const int hq = tid >> 6;

    const int nd = n0 + nl;
    const size_t ntbase = ((size_t)((nd >> 5) * 4 + ((nd >> 3) & 3)) * 1024) * 8 + (nd & 7);

#pragma unroll 1
    for (int bi = 0; bi < 4; ++bi) {
        const int b = b0 + bi;
        if (bi) __syncthreads();
        if (tid < 128) {
            const int which = tid >> 6, nls = tid & 63;
            axs[which][nls] = AX[(size_t)(n0 + nls) * XCOLS + (b * TT + 0) * CIN + which];
        }
        __syncthreads();

        const float ax0 = axs[0][nl], ax1 = axs[1][nl];
        float cn[8], hn[8];
#pragma unroll
        for (int u = 0; u < 8; ++u) {
            const int h = hq * 8 + u;
            float a0 = bfl[h * 4 + 0] + ax0 * wxr[h * 4 + 0] + ax1 * wxr[128 + h * 4 + 0];
            float a1 = bfl[h * 4 + 1] + ax0 * wxr[h * 4 + 1] + ax1 * wxr[128 + h * 4 + 1];
            float a2 = bfl[h * 4 + 2] + ax0 * wxr[h * 4 + 2] + ax1 * wxr[128 + h * 4 + 2];
            float a3 = bfl[h * 4 + 3] + ax0 * wxr[h * 4 + 3] + ax1 * wxr[128 + h * 4 + 3];
            const float i_ = 1.0f / (1.0f + expf(-a0));
            const float f_ = 1.0f / (1.0f + expf(-a1));
            const float o_ = 1.0f / (1.0f + expf(-a2));
            const float g_ = tanhf(a3);
            const float ct = i_ * g_;          // c_old = 0
            (void)f_;
            cn[u] = ct;
            hn[u] = o_ * tanhf(ct);
        }
        const size_t off = (size_t)nd * HCOLS + b * HH + hq * 8;
        *(float4*)(c + off)       = make_float4(cn[0], cn[1], cn[2], cn[3]);
        *(float4*)(c + off + 4)   = make_float4(cn[4], cn[5], cn[6], cn[7]);
        *(float4*)(h32 + off)     = make_float4(hn[0], hn[1], hn[2], hn[3]);
        *(float4*)(h32 + off + 4) = make_float4(hn[4], hn[5], hn[6], hn[7]);
#pragma unroll
        for (int u = 0; u < 8; ++u)
            hT[ntbase + (size_t)(b * HH + hq * 8 + u) * 8] = (_Float16)hn[u];
    }
}

// ---------------------------------------------------------------------------
// Kernel 5: out[b][th][n] = bp[th] + sum_k h[n][b*H+k] * Wp[k][th]
// ---------------------------------------------------------------------------
__global__ __launch_bounds__(256) void head_kernel(const float* __restrict__ h,
                                                   const float* __restrict__ Wp,
                                                   const float* __restrict__ bp,
                                                   float* __restrict__ out) {
    const int idx = blockIdx.x * 256 + threadIdx.x;
    const int b = idx >> 11;
    const int n = idx & (NN - 1);
    float hv[HH];
    const float* hp = h + (size_t)n * HCOLS + b * HH;
#pragma unroll
    for (int k = 0; k < HH; ++k) hv[k] = hp[k];
#pragma unroll
    for (int th = 0; th < HOR; ++th) {
        float acc = bp[th];
#pragma unroll
        for (int k = 0; k < HH; ++k) acc += hv[k] * Wp[k * HOR + th];
        out[((size_t)b * HOR + th) * NN + n] = acc;
    }
}

// ---------------------------------------------------------------------------
extern "C" void kernel_launch(void* const* d_in, const int* in_sizes, int n_in,
                              void* d_out, int out_size, void* d_ws, size_t ws_size,
                              hipStream_t stream) {
    const float* x  = (const float*)d_in[0];
    const float* E1 = (const float*)d_in[1];
    const float* E2 = (const float*)d_in[2];
    const float* Wx = (const float*)d_in[3];
    const float* bx = (const float*)d_in[4];
    const float* Wh = (const float*)d_in[5];
    const float* bh = (const float*)d_in[6];
    const float* Wp = (const float*)d_in[7];
    const float* bp = (const float*)d_in[8];

    char* ws = (char*)d_ws;
    _Float16* A2  = (_Float16*)(ws);                    //  8 MB  tiled A
    _Float16* B2x = (_Float16*)(ws + ( 8ull << 20));    //  8 MB  tiled x hi/lo
    _Float16* hT0 = (_Float16*)(ws + (16ull << 20));    //  4 MB  tiled h (ping)
    _Float16* hT1 = (_Float16*)(ws + (20ull << 20));    //  4 MB  tiled h (pong)
    float* AX   = (float*)(ws + (24ull << 20));         //  8 MB
    float* cst  = (float*)(ws + (32ull << 20));         //  8 MB
    float* h32  = (float*)(ws + (40ull << 20));         //  8 MB
    float* Wxr  = (float*)(ws + (48ull << 20) + 65536);
    float* bfold= (float*)(ws + (48ull << 20) + 131072);
    _Float16* W16 = (_Float16*)(ws + (48ull << 20) + 262144);  // 32 KB hi+lo
    _Float16* hTb[2] = {hT0, hT1};

    adj_softmax<<<NN, 256, 0, stream>>>(E1, E2, A2);
    transpose_x<<<(XCOLS * NN) / 256, 256, 0, stream>>>(x, B2x);
    prep_weights<<<1, 256, 0, stream>>>(Wx, bx, Wh, bh, W16, Wxr, bfold);

    // x path: AX = A*Xhi + A*Xlo, written directly (no partials)
    gemm_fused<2, 0><<<256, 512, 0, stream>>>(A2, B2x, AX, nullptr, nullptr, nullptr,
                                              nullptr, nullptr, nullptr, nullptr, 0, 0);

    // t = 0: gates from AX only
    gate_update<<<dim3(NN / 64, BB / 4), 256, 0, stream>>>(AX, Wxr, bfold,
                                                           cst, h32, hTb[0]);
    // t = 1..15: fused GEMM + MFMA gate epilogue; hT ping-pong
    for (int t = 1; t < TT; ++t) {
        gemm_fused<1, 1><<<256, 512, 0, stream>>>(A2, hTb[(t + 1) & 1], nullptr, AX,
                                                  W16, Wxr, bfold, cst, h32,
                                                  hTb[t & 1], t, t == TT - 1 ? 1 : 0);
    }

    head_kernel<<<(BB * NN) / 256, 256, 0, stream>>>(h32, Wp, bp, (float*)d_out);
}

// Round 10
// 558.807 us; speedup vs baseline: 1.5854x; 1.0914x over previous
//
#include <hip/hip_runtime.h>
#include <hip/hip_bf16.h>
#include <cstddef>
#include <cstdint>

#define NN 2048      // nodes (M and K of the big GEMMs)
#define CIN 2
#define HH 32        // hidden
#define EMB 16
#define HOR 12
#define BB 32        // batch
#define TT 16        // time steps
#define GC 128       // 4*HH gate channels
#define XCOLS 1024   // B*T*C
#define HCOLS 1024   // B*H  (GEMM N dim)

// Tiled fp16 operand layouts (32-k tiles, 8-elem chunks), matching the GEMM's
// LDS layout exactly so staging is a LINEAR contiguous copy (and therefore
// directly expressible as global_load_lds: uniform LDS base + lane*16):
//   A2t [tt=64][ko=4][row=2048][e=8] : elem ((tt*4+ko)*2048+row)*8+e = A[row][tt*32+ko*8+e]
//   hTt [tt=64][ko=4][col=1024][e=8] : elem ((tt*4+ko)*1024+col)*8+e = h[node=tt*32+ko*8+e][col]
//   B2xt: hi plane same shape as hTt; lo plane at +LOPLANE elements.
#define ATILE_STRIDE 65536   // 4*2048*8 elements per 32-k tile of A
#define BTILE_STRIDE 32768   // 4*1024*8 elements per 32-k tile of B
#define LOPLANE 2097152      // elements per x plane (64*4*1024*8)

typedef __attribute__((ext_vector_type(8))) _Float16 f16x8;
typedef __attribute__((ext_vector_type(16))) float f32x16;

__device__ __forceinline__ void load_lds16(const void* g, void* l) {
    __builtin_amdgcn_global_load_lds(
        (const __attribute__((address_space(1))) void*)g,
        (__attribute__((address_space(3))) void*)l, 16, 0, 0);
}

// ---------------------------------------------------------------------------
// Kernel 1: A = softmax(relu(E1 @ E2^T)) -> A2t tiled fp16
// ---------------------------------------------------------------------------
__global__ __launch_bounds__(256) void adj_softmax(const float* __restrict__ E1,
                                                   const float* __restrict__ E2,
                                                   _Float16* __restrict__ A2) {
    const int i = blockIdx.x;
    __shared__ float red[256];
    float e1[EMB];
#pragma unroll
    for (int k = 0; k < EMB; ++k) e1[k] = E1[i * EMB + k];

    float s[8];
    float mx = -1e30f;
#pragma unroll
    for (int q = 0; q < 8; ++q) {
        const int j = q * 256 + threadIdx.x;
        float d = 0.f;
#pragma unroll
        for (int k = 0; k < EMB; ++k) d += e1[k] * E2[j * EMB + k];
        d = fmaxf(d, 0.0f);
        s[q] = d;
        mx = fmaxf(mx, d);
    }
    red[threadIdx.x] = mx;
    __syncthreads();
    for (int off = 128; off > 0; off >>= 1) {
        if (threadIdx.x < off) red[threadIdx.x] = fmaxf(red[threadIdx.x], red[threadIdx.x + off]);
        __syncthreads();
    }
    mx = red[0];
    __syncthreads();

    float sum = 0.f;
#pragma unroll
    for (int q = 0; q < 8; ++q) { s[q] = expf(s[q] - mx); sum += s[q]; }
    red[threadIdx.x] = sum;
    __syncthreads();
    for (int off = 128; off > 0; off >>= 1) {
        if (threadIdx.x < off) red[threadIdx.x] += red[threadIdx.x + off];
        __syncthreads();
    }
    const float inv = 1.0f / red[0];
#pragma unroll
    for (int q = 0; q < 8; ++q) {
        const int j  = q * 256 + threadIdx.x;      // k-index of A row i
        const int tt = j >> 5, ko = (j >> 3) & 3, e = j & 7;
        A2[((size_t)(tt * 4 + ko) * 2048 + i) * 8 + e] = (_Float16)(s[q] * inv);
    }
}

// ---------------------------------------------------------------------------
// Kernel 2: x -> B2xt tiled hi/lo fp16 planes (col = (b*T+t)*C + c).
// ---------------------------------------------------------------------------
__global__ __launch_bounds__(256) void transpose_x(const float* __restrict__ x,
                                                   _Float16* __restrict__ B2x) {
    const int idx = blockIdx.x * 256 + threadIdx.x;
    const int col = idx >> 11;
    const int j   = idx & (NN - 1);               // node index (gemm K dim)
    const int bt  = col >> 1;
    const int c   = col & 1;
    const float v = x[((size_t)bt * NN + j) * CIN + c];
    const _Float16 hi = (_Float16)v;
    const _Float16 lo = (_Float16)(v - (float)hi);
    const int tt = j >> 5, ko = (j >> 3) & 3, e = j & 7;
    const size_t base = ((size_t)(tt * 4 + ko) * 1024 + col) * 8 + e;
    B2x[base] = hi; B2x[base + LOPLANE] = lo;
}

// ---------------------------------------------------------------------------
// Kernel 3: fused full-K fp16 MFMA GEMM (32x32x16) + MFMA gate epilogue.
// Tile M=64 x N=128, K=2048. Grid 256, 1 block/CU, 8 waves (mi 2 x gq 4).
// ROUND 10 K-loop (NPROD=1): BK=64 (SUBS=2 subtiles/step, NT=32 steps) —
// halves the step count to amortize the per-step barrier/schedule overhead
// (the ~900cyc/step invariant of rounds 3-8). 4 LDS buffers x 24KB, depth-2
// prefetch, uniform 3 DMA-groups/wave -> branchless counted vmcnt(6).
// NPROD=2 (x path): round 7's proven BK=32 / 6-buffer / depth-3 loop.
// WAR-safe: STAGE targets buf (it+2)&3 == buf(it-2), whose readers finished
// before barrier(it-1). Final COMPUTE reads buf 3 (73728+), disjoint from
// the epilogue's ahh/ahl/gl overlay (0..68608).
// GATE epilogue (round 8, unchanged): hi/lo-split MFMA gate GEMM + LSTM
// pointwise; writes c, tiled hT (ping-pong), h32 on last step.
// XCD swizzle: XCD owns 8 mb x 4 nb -> 2MB A-slab + 2MB hT-cols in L2.
// ---------------------------------------------------------------------------
template <int NPROD, int GATE>
__global__ __launch_bounds__(512, 2) void gemm_fused(const _Float16* __restrict__ A2,
                                                     const _Float16* __restrict__ B2,
                                                     float* __restrict__ Cout,
                                                     const float* __restrict__ AX,
                                                     const _Float16* __restrict__ W16,
                                                     const float* __restrict__ Wxr,
                                                     const float* __restrict__ bfold,
                                                     float* __restrict__ cst,
                                                     float* __restrict__ h32,
                                                     _Float16* __restrict__ hTout,
                                                     int t, int last) {
    constexpr int SUBS   = (NPROD == 1) ? 2 : 1;     // 32k-subtiles per step
    constexpr int NT     = 64 / SUBS;                // K-steps
    constexpr int SUBBUF = 4096 + NPROD * 8192;      // bytes per 32k-subtile
    constexpr int BUF    = SUBS * SUBBUF;            // 24576 | 20480
    constexpr int NBUF   = (NPROD == 1) ? 4 : 6;
    constexpr int PCH    = 256 + NPROD * 512;        // chunks per subtile
    constexpr int NG     = (SUBS * PCH) / 64;        // groups/step: 24 | 20
    constexpr int GMAX   = 3;                        // groups per wave
    constexpr int STAGE_SZ = NBUF * BUF;             // 98304 | 122880
    constexpr int SMEMSZ = GATE ? (STAGE_SZ + 1024 + 512 + 2048) : STAGE_SZ;
    __shared__ __align__(16) char smem[SMEMSZ];

    const int tid  = threadIdx.x;
    const int w    = tid >> 6;
    const int lane = tid & 63;

    // XCD-aware decomposition: physical XCD = wg & 7 (round-robin dispatch).
    const int wg = blockIdx.x;
    const int x8 = wg & 7;
    const int s  = wg >> 3;                 // 0..31 slot within XCD
    const int mb = (x8 >> 1) * 8 + (s & 7);
    const int nb = (x8 & 1) * 4 + (s >> 3);
    const int m0 = mb * 64;
    const int n0 = nb * 128;

    float* wxr_s = nullptr; float* bfl_s = nullptr; float* axs = nullptr;
    if constexpr (GATE) {
        wxr_s = (float*)(smem + STAGE_SZ);
        bfl_s = (float*)(smem + STAGE_SZ + 1024);
        axs   = (float*)(smem + STAGE_SZ + 1536);   // [bi 4][which 2][nl 64]
        const int b0c = nb * 4;
        if (tid < 64) *(float4*)&wxr_s[tid * 4] = *(const float4*)&Wxr[tid * 4];
        if (tid < 32) *(float4*)&bfl_s[tid * 4] = *(const float4*)&bfold[tid * 4];
        axs[tid] = AX[(size_t)(m0 + (tid & 63)) * XCOLS +
                      ((b0c + (tid >> 7)) * TT + t) * CIN + ((tid >> 6) & 1)];
    }

    // ---- per-wave staging groups. Group g covers chunks [g*64, g*64+64):
    // chunk cid -> subtile su = cid/PCH, r = cid%PCH.
    //   r <  256: A chunk (ko=r>>6, row=r&63), LDS off = su*SUBBUF + r*16
    //   r >= 256: B chunk r2=r-256 (plane=r2>>9, ko=(r2&511)>>7, col=r2&127),
    //             LDS off = su*SUBBUF + 4096 + r2*16
    // Region boundaries (256, PCH) are multiples of 64 -> no straddle.
    const _Float16* gp[GMAX];
    int lbase[GMAX];
    int adv[GMAX];
    bool val[GMAX];
#pragma unroll
    for (int i = 0; i < GMAX; ++i) {
        const int g = w + 8 * i;
        val[i] = (g < NG);
        const int gg = val[i] ? g : 0;
        const int cid  = gg * 64 + lane;
        const int cid0 = gg * 64;
        const int su  = cid / PCH,  r  = cid  - su * PCH;
        const int su0 = cid0 / PCH, r0 = cid0 - su0 * PCH;
        if (r < 256) {
            gp[i]  = A2 + ((size_t)((su * 4 + (r >> 6)) * 2048) + m0 + (r & 63)) * 8;
            adv[i] = SUBS * ATILE_STRIDE;
        } else {
            const int r2 = r - 256;
            gp[i]  = B2 + (size_t)(r2 >> 9) * LOPLANE
                        + ((size_t)((su * 4 + ((r2 & 511) >> 7)) * 1024) + n0 + (r2 & 127)) * 8;
            adv[i] = SUBS * BTILE_STRIDE;
        }
        lbase[i] = su0 * SUBBUF + (r0 < 256 ? r0 * 16 : 4096 + (r0 - 256) * 16);
    }

    // ---- fragment offsets: 8 waves = (mi = w>>2) x (gq = w&3).
    const int lrow = lane & 31, lg = lane >> 5;
    const int mi = w >> 2;
    const int gq = w & 3;
    const int wc = gq * 32;
    const int aoff0 = lg * 1024 + (mi * 32 + lrow) * 16;           // ks=0
    const int aoff1 = 2048 + lg * 1024 + (mi * 32 + lrow) * 16;    // ks=1
    const int boff0 = 4096 + lg * 2048 + (wc + lrow) * 16;
    const int boff1 = 4096 + 4096 + lg * 2048 + (wc + lrow) * 16;

    f32x16 acc0 = (f32x16)(0.0f), acc1 = (f32x16)(0.0f);

#define STAGE(BUFI) do {                                                       \
    char* lb = smem + (BUFI) * BUF;                                            \
    _Pragma("unroll")                                                          \
    for (int i = 0; i < GMAX; ++i) if (val[i]) {                               \
        load_lds16(gp[i], lb + lbase[i]);                                      \
        gp[i] += adv[i];                                                       \
    }                                                                          \
} while (0)

#define VMW(NHI, NLO) do {                                                     \
    if (w < 4) asm volatile("s_waitcnt vmcnt(" #NHI ")" ::: "memory");         \
    else       asm volatile("s_waitcnt vmcnt(" #NLO ")" ::: "memory");         \
} while (0)

#define BAR() do {                                                             \
    __builtin_amdgcn_s_barrier();                                              \
    asm volatile("" ::: "memory");                                             \
} while (0)

#define COMPUTE(BUFI) do {                                                     \
    const char* sb = smem + (BUFI) * BUF;                                      \
    _Pragma("unroll")                                                          \
    for (int su = 0; su < SUBS; ++su) {                                        \
        const char* st = sb + su * SUBBUF;                                     \
        f16x8 fa0 = *(const f16x8*)(st + aoff0);                               \
        f16x8 fa1 = *(const f16x8*)(st + aoff1);                               \
        f16x8 fb0 = *(const f16x8*)(st + boff0);                               \
        f16x8 fb1 = *(const f16x8*)(st + boff1);                               \
        acc0 = __builtin_amdgcn_mfma_f32_32x32x16_f16(fa0, fb0, acc0, 0, 0, 0);\
        acc1 = __builtin_amdgcn_mfma_f32_32x32x16_f16(fa1, fb1, acc1, 0, 0, 0);\
        if constexpr (NPROD == 2) {                                            \
            f16x8 fc0 = *(const f16x8*)(st + boff0 + 8192);                    \
            f16x8 fc1 = *(const f16x8*)(st + boff1 + 8192);                    \
            acc0 = __builtin_amdgcn_mfma_f32_32x32x16_f16(fa0, fc0, acc0, 0, 0, 0); \
            acc1 = __builtin_amdgcn_mfma_f32_32x32x16_f16(fa1, fc1, acc1, 0, 0, 0); \
        }                                                                      \
    }                                                                          \
} while (0)

    if constexpr (NPROD == 1) {
        // BK=64, 4 buffers, depth-2, uniform 3 loads/wave/step -> vmcnt(6)
        STAGE(0);
        STAGE(1);
#pragma unroll 1
        for (int it = 0; it < NT - 2; ++it) {
            STAGE((it + 2) & 3);
            asm volatile("s_waitcnt vmcnt(6)" ::: "memory");
            BAR();
            COMPUTE(it & 3);
        }
        asm volatile("s_waitcnt vmcnt(3)" ::: "memory");
        BAR();
        COMPUTE((NT - 2) & 3);
        asm volatile("s_waitcnt vmcnt(0)" ::: "memory");
        BAR();
        COMPUTE((NT - 1) & 3);          // buf 3 @73728+: disjoint from ah/gl
    } else {
        // BK=32, 6 buffers, depth-3 (round 7 verbatim)
        STAGE(0);
        STAGE(1);
        STAGE(2);
        int bs = 3, bc = 0;
#pragma unroll 1
        for (int it = 0; it < NT - 3; ++it) {
            STAGE(bs);
            VMW(9, 6);
            BAR();
            COMPUTE(bc);
            bs = (bs == 5) ? 0 : bs + 1;
            bc = (bc == 5) ? 0 : bc + 1;
        }
        VMW(6, 4);
        BAR();
        COMPUTE(bc); bc = (bc == 5) ? 0 : bc + 1;
        VMW(3, 2);
        BAR();
        COMPUTE(bc); bc = (bc == 5) ? 0 : bc + 1;
        asm volatile("s_waitcnt vmcnt(0)" ::: "memory");
        BAR();
        COMPUTE(bc);
    }
#undef STAGE
#undef VMW
#undef BAR
#undef COMPUTE

    // ---- C layout per 32x32 acc: col=lane&31, row=(r&3)+8*(r>>2)+4*lg ----
    if constexpr (!GATE) {
        const int colg = n0 + wc + lrow;
#pragma unroll
        for (int r = 0; r < 16; ++r) {
            const int rp = (r & 3) + 8 * (r >> 2) + 4 * lg;
            Cout[(size_t)(m0 + mi * 32 + rp) * XCOLS + colg] = acc0[r] + acc1[r];
        }
    } else {
        // -- W-frag loads (L2-resident)
        f16x8 wbh0 = *(const f16x8*)(W16 + ((size_t)(0 * 4 + gq) * 64 + lane) * 8);
        f16x8 wbh1 = *(const f16x8*)(W16 + ((size_t)(1 * 4 + gq) * 64 + lane) * 8);
        f16x8 wbl0 = *(const f16x8*)(W16 + 8192 + ((size_t)(0 * 4 + gq) * 64 + lane) * 8);
        f16x8 wbl1 = *(const f16x8*)(W16 + 8192 + ((size_t)(1 * 4 + gq) * 64 + lane) * 8);

        // -- stage Ah as hi/lo fp16 planes [64][136] (overlay bufs 0-2;
        //    safe: all waves passed the final pre-COMPUTE barrier, and the
        //    final COMPUTE reads only buf 3)
        _Float16* ahh = (_Float16*)smem;
        _Float16* ahl = (_Float16*)(smem + 17408);
        const int colw = wc + lrow;
#pragma unroll
        for (int r = 0; r < 16; ++r) {
            const int rp = (r & 3) + 8 * (r >> 2) + 4 * lg;
            const float v = acc0[r] + acc1[r];
            const _Float16 hi = (_Float16)v;
            ahh[(mi * 32 + rp) * 136 + colw] = hi;
            ahl[(mi * 32 + rp) * 136 + colw] = (_Float16)(v - (float)hi);
        }
        __syncthreads();

        // -- gate GEMM: wave (mi, gq) computes [32n x 32ch] for each b
        f32x16 g0 = (f32x16)(0.0f), g1 = (f32x16)(0.0f);
        f32x16 g2 = (f32x16)(0.0f), g3 = (f32x16)(0.0f);
#define GATEB(ACC, b) do {                                                         \
    const int arow = (mi * 32 + lrow) * 136 + (b) * 32 + lg * 8;                   \
    f16x8 fh0 = *(const f16x8*)(ahh + arow);                                       \
    f16x8 fl0 = *(const f16x8*)(ahl + arow);                                       \
    f16x8 fh1 = *(const f16x8*)(ahh + arow + 16);                                  \
    f16x8 fl1 = *(const f16x8*)(ahl + arow + 16);                                  \
    ACC = __builtin_amdgcn_mfma_f32_32x32x16_f16(fh0, wbh0, ACC, 0, 0, 0);         \
    ACC = __builtin_amdgcn_mfma_f32_32x32x16_f16(fh0, wbl0, ACC, 0, 0, 0);         \
    ACC = __builtin_amdgcn_mfma_f32_32x32x16_f16(fl0, wbh0, ACC, 0, 0, 0);         \
    ACC = __builtin_amdgcn_mfma_f32_32x32x16_f16(fh1, wbh1, ACC, 0, 0, 0);         \
    ACC = __builtin_amdgcn_mfma_f32_32x32x16_f16(fh1, wbl1, ACC, 0, 0, 0);         \
    ACC = __builtin_amdgcn_mfma_f32_32x32x16_f16(fl1, wbh1, ACC, 0, 0, 0);         \
} while (0)
        GATEB(g0, 0); GATEB(g1, 1); GATEB(g2, 2); GATEB(g3, 3);
#undef GATEB

        // -- per-b: stage gate tile to LDS f32 [64][132]; pointwise LSTM
        float* gl = (float*)(smem + 34816);
        const int nl2 = tid & 63;
        const int hb  = (tid >> 6) * 4;
        const int b0c = nb * 4;
        const int nd  = m0 + nl2;
        const size_t ntbase = ((size_t)((nd >> 5) * 4 + ((nd >> 3) & 3)) * 1024) * 8 + (nd & 7);

#define POINT(ACC, bi) do {                                                        \
    _Pragma("unroll")                                                              \
    for (int r = 0; r < 16; ++r) {                                                 \
        const int rp = (r & 3) + 8 * (r >> 2) + 4 * lg;                            \
        gl[(mi * 32 + rp) * 132 + gq * 32 + lrow] = ACC[r];                        \
    }                                                                              \
    __syncthreads();                                                               \
    {                                                                              \
        const float ax0 = axs[(bi) * 128 + nl2];                                   \
        const float ax1 = axs[(bi) * 128 + 64 + nl2];                              \
        const int bb = b0c + (bi);                                                 \
        const size_t off = (size_t)nd * HCOLS + bb * HH + hb;                      \
        const float4 co = *(const float4*)(cst + off);                             \
        const float cold[4] = {co.x, co.y, co.z, co.w};                            \
        float cn[4], hn[4];                                                        \
        _Pragma("unroll")                                                          \
        for (int p = 0; p < 4; ++p) {                                              \
            const int hh = hb + p;                                                 \
            const float4 gt = *(const float4*)(gl + nl2 * 132 + hh * 4);           \
            const float a0 = gt.x + bfl_s[hh*4+0] + ax0*wxr_s[hh*4+0] + ax1*wxr_s[128+hh*4+0]; \
            const float a1 = gt.y + bfl_s[hh*4+1] + ax0*wxr_s[hh*4+1] + ax1*wxr_s[128+hh*4+1]; \
            const float a2 = gt.z + bfl_s[hh*4+2] + ax0*wxr_s[hh*4+2] + ax1*wxr_s[128+hh*4+2]; \
            const float a3 = gt.w + bfl_s[hh*4+3] + ax0*wxr_s[hh*4+3] + ax1*wxr_s[128+hh*4+3]; \
            const float i_ = 1.0f / (1.0f + expf(-a0));                            \
            const float f_ = 1.0f / (1.0f + expf(-a1));                            \
            const float o_ = 1.0f / (1.0f + expf(-a2));                            \
            const float g_ = tanhf(a3);                                            \
            const float ct = f_ * cold[p] + i_ * g_;                               \
            cn[p] = ct;                                                            \
            hn[p] = o_ * tanhf(ct);                                                \
        }                                                                          \
        *(float4*)(cst + off) = make_float4(cn[0], cn[1], cn[2], cn[3]);           \
        if (last) *(float4*)(h32 + off) = make_float4(hn[0], hn[1], hn[2], hn[3]); \
        _Pragma("unroll")                                                          \
        for (int p = 0; p < 4; ++p)                                                \
            hTout[ntbase + (size_t)(bb * HH + hb + p) * 8] = (_Float16)hn[p];      \
    }                                                                              \
    __syncthreads();                                                               \
} while (0)
        POINT(g0, 0); POINT(g1, 1); POINT(g2, 2); POINT(g3, 3);
#undef POINT
    }
}

// ---------------------------------------------------------------------------
// Kernel 3c: weight prep. W16 hi/lo = Wh split into MFMA B-frag tables
// ([kh 2][gq 4][lane 64][e 8], hi at 0, lo at +8192); Wxr[c][h][g]; bfold.
// ---------------------------------------------------------------------------
__global__ __launch_bounds__(256) void prep_weights(const float* __restrict__ Wx,
                                                    const float* __restrict__ bx,
                                                    const float* __restrict__ Wh,
                                                    const float* __restrict__ bh,
                                                    _Float16* __restrict__ W16,
                                                    float* __restrict__ Wxr,
                                                    float* __restrict__ bfold) {
    const int tid = threadIdx.x;
#pragma unroll
    for (int r = 0; r < 32; ++r) {
        const int idx = r * 256 + tid;          // 8192 frag entries
        const int e  = idx & 7;
        const int ln = (idx >> 3) & 63;
        const int gq = (idx >> 9) & 3;
        const int kh = (idx >> 11) & 1;
        const int k  = kh * 16 + (ln >> 5) * 8 + e;
        const int ch = gq * 32 + (ln & 31);     // channel = h*4 + gate
        const float v = Wh[k * GC + (ch & 3) * HH + (ch >> 2)];
        const _Float16 hi = (_Float16)v;
        W16[idx] = hi;
        W16[8192 + idx] = (_Float16)(v - (float)hi);
    }
    {
        const int idx = tid;                    // 256
        const int c = idx >> 7, rem = idx & 127;
        const int h = rem >> 2, g = rem & 3;
        Wxr[idx] = Wx[c * GC + g * HH + h];
    }
    if (tid < 128) {
        const int h = tid >> 2, g = tid & 3;
        bfold[tid] = bx[g * HH + h] + bh[g * HH + h];
    }
}

// ---------------------------------------------------------------------------
// Kernel 4: t=0 gate update only (no recurrent term), 64 nodes x 4 batches.
// ---------------------------------------------------------------------------
__global__ __launch_bounds__(256) void gate_update(const float* __restrict__ AX,
                                                   const float* __restrict__ Wxr,
                                                   const float* __restrict__ bfold,
                                                   float* __restrict__ c,
                                                   float* __restrict__ h32,
                                                   _Float16* __restrict__ hT) {
    const int n0 = blockIdx.x * 64;
    const int b0 = blockIdx.y * 4;
    const int tid = threadIdx.x;
    __shared__ float wxr[256];
    __shared__ float bfl[128];
    __shared__ float axs[2][64];

    if (tid < 64)  *(float4*)&wxr[tid * 4] = *(const float4*)&Wxr[tid * 4];
    if (tid < 32)  *(float4*)&bfl[tid * 4] = *(const float4*)&bfold[tid * 4];

    const int nl = tid & 63;
    const int hq = tid >> 6;

    const int nd = n0 + nl;
    const size_t ntbase = ((size_t)((nd >> 5) * 4 + ((nd >> 3) & 3)) * 1024) * 8 + (nd & 7);

#pragma unroll 1
    for (int bi = 0; bi < 4; ++bi) {
        const int b = b0 + bi;
        if (bi) __syncthreads();
        if (tid < 128) {
            const int which = tid >> 6, nls = tid & 63;
            axs[which][nls] = AX[(size_t)(n0 + nls) * XCOLS + (b * TT + 0) * CIN + which];
        }
        __syncthreads();

        const float ax0 = axs[0][nl], ax1 = axs[1][nl];
        float cn[8], hn[8];
#pragma unroll
        for (int u = 0; u < 8; ++u) {
            const int h = hq * 8 + u;
            float a0 = bfl[h * 4 + 0] + ax0 * wxr[h * 4 + 0] + ax1 * wxr[128 + h * 4 + 0];
            float a1 = bfl[h * 4 + 1] + ax0 * wxr[h * 4 + 1] + ax1 * wxr[128 + h * 4 + 1];
            float a2 = bfl[h * 4 + 2] + ax0 * wxr[h * 4 + 2] + ax1 * wxr[128 + h * 4 + 2];
            float a3 = bfl[h * 4 + 3] + ax0 * wxr[h * 4 + 3] + ax1 * wxr[128 + h * 4 + 3];
            const float i_ = 1.0f / (1.0f + expf(-a0));
            const float f_ = 1.0f / (1.0f + expf(-a1));
            const float o_ = 1.0f / (1.0f + expf(-a2));
            const float g_ = tanhf(a3);
            const float ct = i_ * g_;          // c_old = 0
            (void)f_;
            cn[u] = ct;
            hn[u] = o_ * tanhf(ct);
        }
        const size_t off = (size_t)nd * HCOLS + b * HH + hq * 8;
        *(float4*)(c + off)       = make_float4(cn[0], cn[1], cn[2], cn[3]);
        *(float4*)(c + off + 4)   = make_float4(cn[4], cn[5], cn[6], cn[7]);
        *(float4*)(h32 + off)     = make_float4(hn[0], hn[1], hn[2], hn[3]);
        *(float4*)(h32 + off + 4) = make_float4(hn[4], hn[5], hn[6], hn[7]);
#pragma unroll
        for (int u = 0; u < 8; ++u)
            hT[ntbase + (size_t)(b * HH + hq * 8 + u) * 8] = (_Float16)hn[u];
    }
}

// ---------------------------------------------------------------------------
// Kernel 5: out[b][th][n] = bp[th] + sum_k h[n][b*H+k] * Wp[k][th]
// ---------------------------------------------------------------------------
__global__ __launch_bounds__(256) void head_kernel(const float* __restrict__ h,
                                                   const float* __restrict__ Wp,
                                                   const float* __restrict__ bp,
                                                   float* __restrict__ out) {
    const int idx = blockIdx.x * 256 + threadIdx.x;
    const int b = idx >> 11;
    const int n = idx & (NN - 1);
    float hv[HH];
    const float* hp = h + (size_t)n * HCOLS + b * HH;
#pragma unroll
    for (int k = 0; k < HH; ++k) hv[k] = hp[k];
#pragma unroll
    for (int th = 0; th < HOR; ++th) {
        float acc = bp[th];
#pragma unroll
        for (int k = 0; k < HH; ++k) acc += hv[k] * Wp[k * HOR + th];
        out[((size_t)b * HOR + th) * NN + n] = acc;
    }
}

// ---------------------------------------------------------------------------
extern "C" void kernel_launch(void* const* d_in, const int* in_sizes, int n_in,
                              void* d_out, int out_size, void* d_ws, size_t ws_size,
                              hipStream_t stream) {
    const float* x  = (const float*)d_in[0];
    const float* E1 = (const float*)d_in[1];
    const float* E2 = (const float*)d_in[2];
    const float* Wx = (const float*)d_in[3];
    const float* bx = (const float*)d_in[4];
    const float* Wh = (const float*)d_in[5];
    const float* bh = (const float*)d_in[6];
    const float* Wp = (const float*)d_in[7];
    const float* bp = (const float*)d_in[8];

    char* ws = (char*)d_ws;
    _Float16* A2  = (_Float16*)(ws);                    //  8 MB  tiled A
    _Float16* B2x = (_Float16*)(ws + ( 8ull << 20));    //  8 MB  tiled x hi/lo
    _Float16* hT0 = (_Float16*)(ws + (16ull << 20));    //  4 MB  tiled h (ping)
    _Float16* hT1 = (_Float16*)(ws + (20ull << 20));    //  4 MB  tiled h (pong)
    float* AX   = (float*)(ws + (24ull << 20));         //  8 MB
    float* cst  = (float*)(ws + (32ull << 20));         //  8 MB
    float* h32  = (float*)(ws + (40ull << 20));         //  8 MB
    float* Wxr  = (float*)(ws + (48ull << 20) + 65536);
    float* bfold= (float*)(ws + (48ull << 20) + 131072);
    _Float16* W16 = (_Float16*)(ws + (48ull << 20) + 262144);  // 32 KB hi+lo
    _Float16* hTb[2] = {hT0, hT1};

    adj_softmax<<<NN, 256, 0, stream>>>(E1, E2, A2);
    transpose_x<<<(XCOLS * NN) / 256, 256, 0, stream>>>(x, B2x);
    prep_weights<<<1, 256, 0, stream>>>(Wx, bx, Wh, bh, W16, Wxr, bfold);

    // x path: AX = A*Xhi + A*Xlo, written directly (no partials)
    gemm_fused<2, 0><<<256, 512, 0, stream>>>(A2, B2x, AX, nullptr, nullptr, nullptr,
                                              nullptr, nullptr, nullptr, nullptr, 0, 0);

    // t = 0: gates from AX only
    gate_update<<<dim3(NN / 64, BB / 4), 256, 0, stream>>>(AX, Wxr, bfold,
                                                           cst, h32, hTb[0]);
    // t = 1..15: fused GEMM + MFMA gate epilogue; hT ping-pong
    for (int t = 1; t < TT; ++t) {
        gemm_fused<1, 1><<<256, 512, 0, stream>>>(A2, hTb[(t + 1) & 1], nullptr, AX,
                                                  W16, Wxr, bfold, cst, h32,
                                                  hTb[t & 1], t, t == TT - 1 ? 1 : 0);
    }

    head_kernel<<<(BB * NN) / 256, 256, 0, stream>>>(h32, Wp, bp, (float*)d_out);
}